// Round 1
// baseline (893.227 us; speedup 1.0000x reference)
//
#include <hip/hip_runtime.h>
#include <math.h>

// Problem constants
#define B 64
#define S 2048
#define H 1024
#define E 512
#define V 32000
#define G4 4096        // 4*H
#define KX 1536        // E+H
#define KC 2560        // E+H+H

// ---------------- K0a: hwh[b] = dot(prev_h[b,:], attn_W[0:H]) ----------------
__global__ __launch_bounds__(256) void hwh_kernel(const float* __restrict__ prev_h,
                                                  const float* __restrict__ attn_W,
                                                  float* __restrict__ hwh) {
    __shared__ float red[256];
    int b = blockIdx.x, t = threadIdx.x;
    float4 p = *(const float4*)(prev_h + b * H + t * 4);
    float4 w = *(const float4*)(attn_W + t * 4);
    red[t] = p.x * w.x + p.y * w.y + p.z * w.z + p.w * w.w;
    __syncthreads();
    for (int s2 = 128; s2; s2 >>= 1) {
        if (t < s2) red[t] += red[t + s2];
        __syncthreads();
    }
    if (t == 0) hwh[b] = red[0];
}

// ---------------- K0b: fill xT (transposed x_cat) with emb and prev_h -------
// xT[k][b], k in [0,E) = emb, [E,KX) = context (filled later), [KX,KC) = prev_h
__global__ __launch_bounds__(256) void xfill_kernel(const int* __restrict__ ib,
                                                    const float* __restrict__ emb_W,
                                                    const float* __restrict__ prev_h,
                                                    float* __restrict__ xT) {
    int t = blockIdx.x * 256 + threadIdx.x;   // 98304 threads
    if (t < E * B) {
        int b = t & 63, k = t >> 6;
        xT[k * B + b] = emb_W[(size_t)ib[b] * E + k];
    } else {
        int t2 = t - E * B;
        int b = t2 & 63, k = t2 >> 6;        // k in [0,H)
        xT[(KX + k) * B + b] = prev_h[b * H + k];
    }
}

// ---------------- K1: scores[b,s] = enc[s,b,:]·We + hwh[b] + attn_b ---------
__global__ __launch_bounds__(256) void scores_kernel(const float* __restrict__ enc,
                                                     const float* __restrict__ attn_W,
                                                     const float* __restrict__ attn_b,
                                                     const float* __restrict__ hwh,
                                                     float* __restrict__ scores) {
    int lane = threadIdx.x & 63;
    int w = blockIdx.x * 4 + (threadIdx.x >> 6);  // wave id, 131072 total
    int b = w & 63, s = w >> 6;
    const float* base = enc + (size_t)s * (B * H) + b * H;
    const float* We = attn_W + H;
    float acc = 0.f;
#pragma unroll
    for (int i = 0; i < 4; ++i) {
        int off = i * 256 + lane * 4;
        float4 e = *(const float4*)(base + off);
        float4 wv = *(const float4*)(We + off);
        acc += e.x * wv.x + e.y * wv.y + e.z * wv.z + e.w * wv.w;
    }
#pragma unroll
    for (int m = 32; m; m >>= 1) acc += __shfl_xor(acc, m);
    if (lane == 0) scores[b * S + s] = acc + hwh[b] + attn_b[0];
}

// ---------------- K2: attn[b,:] = softmax(scores[b,:]) ----------------------
__global__ __launch_bounds__(256) void softmax_kernel(const float* __restrict__ scores,
                                                      float* __restrict__ attn) {
    __shared__ float red[256];
    int b = blockIdx.x, t = threadIdx.x;
    float v[8];
    float m = -3.4e38f;
#pragma unroll
    for (int i = 0; i < 8; ++i) {
        v[i] = scores[b * S + t + i * 256];
        m = fmaxf(m, v[i]);
    }
    red[t] = m; __syncthreads();
    for (int s2 = 128; s2; s2 >>= 1) {
        if (t < s2) red[t] = fmaxf(red[t], red[t + s2]);
        __syncthreads();
    }
    m = red[0]; __syncthreads();
    float l = 0.f;
#pragma unroll
    for (int i = 0; i < 8; ++i) {
        v[i] = expf(v[i] - m);
        l += v[i];
    }
    red[t] = l; __syncthreads();
    for (int s2 = 128; s2; s2 >>= 1) {
        if (t < s2) red[t] += red[t + s2];
        __syncthreads();
    }
    float inv = 1.f / red[0];
#pragma unroll
    for (int i = 0; i < 8; ++i) attn[b * S + t + i * 256] = v[i] * inv;
}

// ---------------- K3: partial context over s-chunks -------------------------
// cpart[chunk][b][h] = sum_{s in chunk} attn[b,s] * enc[s,b,h]
__global__ __launch_bounds__(256) void ctx_partial_kernel(const float* __restrict__ enc,
                                                          const float* __restrict__ attn,
                                                          float* __restrict__ cpart) {
    int bx = blockIdx.x;              // 64*32 blocks
    int b = bx >> 5, chunk = bx & 31;
    int s0 = chunk * 64;
    int h0 = threadIdx.x * 4;
    float4 acc = {0.f, 0.f, 0.f, 0.f};
    for (int s = s0; s < s0 + 64; ++s) {
        float w = attn[b * S + s];
        float4 e = *(const float4*)(enc + (size_t)s * (B * H) + b * H + h0);
        acc.x += w * e.x; acc.y += w * e.y; acc.z += w * e.z; acc.w += w * e.w;
    }
    *(float4*)(cpart + (size_t)(chunk * B + b) * H + h0) = acc;
}

// ---------------- K4: reduce partials into xT context slots -----------------
__global__ __launch_bounds__(256) void ctx_reduce_kernel(const float* __restrict__ cpart,
                                                         float* __restrict__ xT) {
    int t = blockIdx.x * 256 + threadIdx.x;  // 65536
    int b = t & 63, h = t >> 6;
    float s = 0.f;
    for (int c = 0; c < 32; ++c) s += cpart[(size_t)(c * B + b) * H + h];
    xT[(E + h) * B + b] = s;
}

// ---------------- K5: gates partial GEMM ------------------------------------
// gpart[ks][r][b] = sum_{k in ks-chunk} Wcat[r,k] * xT[k][b]
__global__ __launch_bounds__(256) void gates_partial_kernel(const float* __restrict__ W_ih,
                                                            const float* __restrict__ W_hh,
                                                            const float* __restrict__ xT,
                                                            float* __restrict__ gpart) {
    int lane = threadIdx.x & 63;
    int w = __builtin_amdgcn_readfirstlane(blockIdx.x * 4 + (threadIdx.x >> 6)); // 2048 waves
    int ks = w & 3;
    int r0 = (w >> 2) * 8;
    int k0 = ks * 640, k1 = k0 + 640;
    float acc[8] = {0.f, 0.f, 0.f, 0.f, 0.f, 0.f, 0.f, 0.f};
    // segment A: W_ih columns [k0, min(k1, KX))
    int kb = k1 < KX ? k1 : KX;
    if (k0 < kb) {
        const float* rows[8];
#pragma unroll
        for (int j = 0; j < 8; ++j) rows[j] = W_ih + (size_t)(r0 + j) * KX;
        for (int k = k0; k < kb; ++k) {
            float xv = xT[k * B + lane];
#pragma unroll
            for (int j = 0; j < 8; ++j) acc[j] += rows[j][k] * xv;
        }
    }
    // segment B: W_hh columns [max(k0, KX), k1)
    int kc = k0 > KX ? k0 : KX;
    if (kc < k1) {
        const float* rows[8];
#pragma unroll
        for (int j = 0; j < 8; ++j) rows[j] = W_hh + (size_t)(r0 + j) * H;
        for (int k = kc; k < k1; ++k) {
            float xv = xT[k * B + lane];
            int kk = k - KX;
#pragma unroll
            for (int j = 0; j < 8; ++j) acc[j] += rows[j][kk] * xv;
        }
    }
#pragma unroll
    for (int j = 0; j < 8; ++j)
        gpart[(size_t)ks * (G4 * B) + (r0 + j) * B + lane] = acc[j];
}

// ---------------- K6: LSTM elementwise --------------------------------------
__global__ __launch_bounds__(256) void lstm_kernel(const float* __restrict__ gpart,
                                                   const float* __restrict__ b_ih,
                                                   const float* __restrict__ b_hh,
                                                   const float* __restrict__ prev_c,
                                                   float* __restrict__ hidden_out,
                                                   float* __restrict__ cell_out,
                                                   float* __restrict__ hT) {
    int t = blockIdx.x * 256 + threadIdx.x;  // 65536
    int b = t & 63, h = t >> 6;
    float g[4];
#pragma unroll
    for (int q = 0; q < 4; ++q) {
        int r = h + q * H;
        float a = b_ih[r] + b_hh[r];
#pragma unroll
        for (int ks = 0; ks < 4; ++ks) a += gpart[(size_t)ks * (G4 * B) + r * B + b];
        g[q] = a;
    }
    float ig = 1.f / (1.f + expf(-g[0]));
    float fg = 1.f / (1.f + expf(-g[1]));
    float gg = tanhf(g[2]);
    float og = 1.f / (1.f + expf(-g[3]));
    float c = fg * prev_c[b * H + h] + ig * gg;
    float hd = og * tanhf(c);
    cell_out[b * H + h] = c;
    hidden_out[b * H + h] = hd;
    hT[h * B + b] = hd;
}

// ---------------- K7: logitsT[v][b] = hidden[b]·out_W[v] + out_b[v] ---------
__global__ __launch_bounds__(256) void logits_kernel(const float* __restrict__ out_W,
                                                     const float* __restrict__ out_b,
                                                     const float* __restrict__ hT,
                                                     float* __restrict__ lT) {
    int lane = threadIdx.x & 63;
    int w = __builtin_amdgcn_readfirstlane(blockIdx.x * 4 + (threadIdx.x >> 6)); // 2000 waves
    int r0 = w * 16;
    float acc[16];
    const float* rows[16];
#pragma unroll
    for (int j = 0; j < 16; ++j) {
        acc[j] = out_b[r0 + j];
        rows[j] = out_W + (size_t)(r0 + j) * H;
    }
    for (int k = 0; k < H; ++k) {
        float xv = hT[k * B + lane];
#pragma unroll
        for (int j = 0; j < 16; ++j) acc[j] += rows[j][k] * xv;
    }
#pragma unroll
    for (int j = 0; j < 16; ++j) lT[(size_t)(r0 + j) * B + lane] = acc[j];
}

// ---------------- K8: log_softmax over V per batch row ----------------------
__global__ __launch_bounds__(1024) void logsoftmax_kernel(const float* __restrict__ lT,
                                                          float* __restrict__ out) {
    __shared__ float red[1024];
    int b = blockIdx.x, t = threadIdx.x;
    float lv[32];
    float m = -3.4e38f;
#pragma unroll
    for (int i = 0; i < 32; ++i) {
        int v = t + i * 1024;
        if (v < V) {
            float x = lT[(size_t)v * B + b];
            lv[i] = x;
            m = fmaxf(m, x);
        } else lv[i] = -3.4e38f;
    }
    red[t] = m; __syncthreads();
    for (int s2 = 512; s2; s2 >>= 1) {
        if (t < s2) red[t] = fmaxf(red[t], red[t + s2]);
        __syncthreads();
    }
    float M = red[0]; __syncthreads();
    float sum = 0.f;
#pragma unroll
    for (int i = 0; i < 32; ++i) {
        int v = t + i * 1024;
        if (v < V) sum += expf(lv[i] - M);
    }
    red[t] = sum; __syncthreads();
    for (int s2 = 512; s2; s2 >>= 1) {
        if (t < s2) red[t] += red[t + s2];
        __syncthreads();
    }
    float c = M + logf(red[0]);
#pragma unroll
    for (int i = 0; i < 32; ++i) {
        int v = t + i * 1024;
        if (v < V) out[(size_t)b * V + v] = lv[i] - c;
    }
}

// ---------------- launch ----------------------------------------------------
extern "C" void kernel_launch(void* const* d_in, const int* in_sizes, int n_in,
                              void* d_out, int out_size, void* d_ws, size_t ws_size,
                              hipStream_t stream) {
    const int*   ib      = (const int*)d_in[0];
    const float* prev_h  = (const float*)d_in[1];
    const float* prev_c  = (const float*)d_in[2];
    const float* enc     = (const float*)d_in[3];
    const float* emb_W   = (const float*)d_in[4];
    const float* attn_W  = (const float*)d_in[5];
    const float* attn_b  = (const float*)d_in[6];
    const float* W_ih    = (const float*)d_in[7];
    const float* W_hh    = (const float*)d_in[8];
    const float* b_ih    = (const float*)d_in[9];
    const float* b_hh    = (const float*)d_in[10];
    const float* out_W   = (const float*)d_in[11];
    const float* out_b   = (const float*)d_in[12];

    float* ws = (float*)d_ws;
    // ws layout (floats) — total 3,506,304 floats = 14.03 MB
    float* sc  = ws;                     // 131072  scores
    float* hwh = ws + 131072;            // 64
    float* xT  = ws + 131200;            // 163840  x_cat transposed [KC][B]
    float* gp  = ws + 295040;            // 1048576 gates partials [4][G4][B]
    float* cp  = ws + 1343616;           // 2097152 context partials [32][B][H]
    float* hT  = ws + 3440768;           // 65536   hidden transposed [H][B]
    float* lT  = cp;                     // logitsT [V][B] reuses cp (dead after K4)

    float* out    = (float*)d_out;
    float* out_ls = out;                         // (B,V)
    float* out_h  = out + (size_t)B * V;         // (B,H)
    float* out_c  = out_h + (size_t)B * H;       // (B,H)
    float* out_a  = out_c + (size_t)B * H;       // (B,S)

    hipLaunchKernelGGL(hwh_kernel,        dim3(B),      dim3(256),  0, stream, prev_h, attn_W, hwh);
    hipLaunchKernelGGL(xfill_kernel,      dim3(384),    dim3(256),  0, stream, ib, emb_W, prev_h, xT);
    hipLaunchKernelGGL(scores_kernel,     dim3(32768),  dim3(256),  0, stream, enc, attn_W, attn_b, hwh, sc);
    hipLaunchKernelGGL(softmax_kernel,    dim3(B),      dim3(256),  0, stream, sc, out_a);
    hipLaunchKernelGGL(ctx_partial_kernel,dim3(2048),   dim3(256),  0, stream, enc, out_a, cp);
    hipLaunchKernelGGL(ctx_reduce_kernel, dim3(256),    dim3(256),  0, stream, cp, xT);
    hipLaunchKernelGGL(gates_partial_kernel, dim3(512), dim3(256),  0, stream, W_ih, W_hh, xT, gp);
    hipLaunchKernelGGL(lstm_kernel,       dim3(256),    dim3(256),  0, stream, gp, b_ih, b_hh, prev_c, out_h, out_c, hT);
    hipLaunchKernelGGL(logits_kernel,     dim3(500),    dim3(256),  0, stream, out_W, out_b, hT, lT);
    hipLaunchKernelGGL(logsoftmax_kernel, dim3(B),      dim3(1024), 0, stream, lT, out_ls);
}

// Round 2
// 557.488 us; speedup vs baseline: 1.6022x; 1.6022x over previous
//
#include <hip/hip_runtime.h>
#include <math.h>

// Problem constants
#define B 64
#define S 2048
#define H 1024
#define E 512
#define V 32000
#define G4 4096        // 4*H
#define KX 1536        // E+H
#define KC 2560        // E+H+H

// ---------------- K0a: hwh[b] = dot(prev_h[b,:], attn_W[0:H]) ----------------
__global__ __launch_bounds__(256) void hwh_kernel(const float* __restrict__ prev_h,
                                                  const float* __restrict__ attn_W,
                                                  float* __restrict__ hwh) {
    __shared__ float red[256];
    int b = blockIdx.x, t = threadIdx.x;
    float4 p = *(const float4*)(prev_h + b * H + t * 4);
    float4 w = *(const float4*)(attn_W + t * 4);
    red[t] = p.x * w.x + p.y * w.y + p.z * w.z + p.w * w.w;
    __syncthreads();
    for (int s2 = 128; s2; s2 >>= 1) {
        if (t < s2) red[t] += red[t + s2];
        __syncthreads();
    }
    if (t == 0) hwh[b] = red[0];
}

// ---------------- K0b: fill xT (transposed x_cat) with emb and prev_h -------
__global__ __launch_bounds__(256) void xfill_kernel(const int* __restrict__ ib,
                                                    const float* __restrict__ emb_W,
                                                    const float* __restrict__ prev_h,
                                                    float* __restrict__ xT) {
    int t = blockIdx.x * 256 + threadIdx.x;   // 98304 threads
    if (t < E * B) {
        int b = t & 63, k = t >> 6;
        xT[k * B + b] = emb_W[(size_t)ib[b] * E + k];
    } else {
        int t2 = t - E * B;
        int b = t2 & 63, k = t2 >> 6;        // k in [0,H)
        xT[(KX + k) * B + b] = prev_h[b * H + k];
    }
}

// ---------------- K1: scores[b,s] = enc[s,b,:]·We + hwh[b] + attn_b ---------
__global__ __launch_bounds__(256) void scores_kernel(const float* __restrict__ enc,
                                                     const float* __restrict__ attn_W,
                                                     const float* __restrict__ attn_b,
                                                     const float* __restrict__ hwh,
                                                     float* __restrict__ scores) {
    int lane = threadIdx.x & 63;
    int w = blockIdx.x * 4 + (threadIdx.x >> 6);  // wave id, 131072 total
    int b = w & 63, s = w >> 6;
    const float* base = enc + (size_t)s * (B * H) + b * H;
    const float* We = attn_W + H;
    float acc = 0.f;
#pragma unroll
    for (int i = 0; i < 4; ++i) {
        int off = i * 256 + lane * 4;
        float4 e = *(const float4*)(base + off);
        float4 wv = *(const float4*)(We + off);
        acc += e.x * wv.x + e.y * wv.y + e.z * wv.z + e.w * wv.w;
    }
#pragma unroll
    for (int m = 32; m; m >>= 1) acc += __shfl_xor(acc, m);
    if (lane == 0) scores[b * S + s] = acc + hwh[b] + attn_b[0];
}

// ---------------- K2: attn[b,:] = softmax(scores[b,:]) ----------------------
__global__ __launch_bounds__(256) void softmax_kernel(const float* __restrict__ scores,
                                                      float* __restrict__ attn) {
    __shared__ float red[256];
    int b = blockIdx.x, t = threadIdx.x;
    float v[8];
    float m = -3.4e38f;
#pragma unroll
    for (int i = 0; i < 8; ++i) {
        v[i] = scores[b * S + t + i * 256];
        m = fmaxf(m, v[i]);
    }
    red[t] = m; __syncthreads();
    for (int s2 = 128; s2; s2 >>= 1) {
        if (t < s2) red[t] = fmaxf(red[t], red[t + s2]);
        __syncthreads();
    }
    m = red[0]; __syncthreads();
    float l = 0.f;
#pragma unroll
    for (int i = 0; i < 8; ++i) {
        v[i] = expf(v[i] - m);
        l += v[i];
    }
    red[t] = l; __syncthreads();
    for (int s2 = 128; s2; s2 >>= 1) {
        if (t < s2) red[t] += red[t + s2];
        __syncthreads();
    }
    float inv = 1.f / red[0];
#pragma unroll
    for (int i = 0; i < 8; ++i) attn[b * S + t + i * 256] = v[i] * inv;
}

// ---------------- K3: partial context over s-chunks -------------------------
__global__ __launch_bounds__(256) void ctx_partial_kernel(const float* __restrict__ enc,
                                                          const float* __restrict__ attn,
                                                          float* __restrict__ cpart) {
    int bx = blockIdx.x;              // 64*32 blocks
    int b = bx >> 5, chunk = bx & 31;
    int s0 = chunk * 64;
    int h0 = threadIdx.x * 4;
    float4 acc = {0.f, 0.f, 0.f, 0.f};
    for (int s = s0; s < s0 + 64; ++s) {
        float w = attn[b * S + s];
        float4 e = *(const float4*)(enc + (size_t)s * (B * H) + b * H + h0);
        acc.x += w * e.x; acc.y += w * e.y; acc.z += w * e.z; acc.w += w * e.w;
    }
    *(float4*)(cpart + (size_t)(chunk * B + b) * H + h0) = acc;
}

// ---------------- K4: reduce partials into xT context slots -----------------
__global__ __launch_bounds__(256) void ctx_reduce_kernel(const float* __restrict__ cpart,
                                                         float* __restrict__ xT) {
    int t = blockIdx.x * 256 + threadIdx.x;  // 65536
    int b = t & 63, h = t >> 6;
    float s = 0.f;
    for (int c = 0; c < 32; ++c) s += cpart[(size_t)(c * B + b) * H + h];
    xT[(E + h) * B + b] = s;
}

// ---------------- K5: gates partial GEMM ------------------------------------
__global__ __launch_bounds__(256) void gates_partial_kernel(const float* __restrict__ W_ih,
                                                            const float* __restrict__ W_hh,
                                                            const float* __restrict__ xT,
                                                            float* __restrict__ gpart) {
    int lane = threadIdx.x & 63;
    int w = __builtin_amdgcn_readfirstlane(blockIdx.x * 4 + (threadIdx.x >> 6)); // 2048 waves
    int ks = w & 3;
    int r0 = (w >> 2) * 8;
    int k0 = ks * 640, k1 = k0 + 640;
    float acc[8] = {0.f, 0.f, 0.f, 0.f, 0.f, 0.f, 0.f, 0.f};
    int kb = k1 < KX ? k1 : KX;
    if (k0 < kb) {
        const float* rows[8];
#pragma unroll
        for (int j = 0; j < 8; ++j) rows[j] = W_ih + (size_t)(r0 + j) * KX;
        for (int k = k0; k < kb; ++k) {
            float xv = xT[k * B + lane];
#pragma unroll
            for (int j = 0; j < 8; ++j) acc[j] += rows[j][k] * xv;
        }
    }
    int kc = k0 > KX ? k0 : KX;
    if (kc < k1) {
        const float* rows[8];
#pragma unroll
        for (int j = 0; j < 8; ++j) rows[j] = W_hh + (size_t)(r0 + j) * H;
        for (int k = kc; k < k1; ++k) {
            float xv = xT[k * B + lane];
            int kk = k - KX;
#pragma unroll
            for (int j = 0; j < 8; ++j) acc[j] += rows[j][kk] * xv;
        }
    }
#pragma unroll
    for (int j = 0; j < 8; ++j)
        gpart[(size_t)ks * (G4 * B) + (r0 + j) * B + lane] = acc[j];
}

// ---------------- K6: LSTM elementwise --------------------------------------
__global__ __launch_bounds__(256) void lstm_kernel(const float* __restrict__ gpart,
                                                   const float* __restrict__ b_ih,
                                                   const float* __restrict__ b_hh,
                                                   const float* __restrict__ prev_c,
                                                   float* __restrict__ hidden_out,
                                                   float* __restrict__ cell_out,
                                                   float* __restrict__ hT) {
    int t = blockIdx.x * 256 + threadIdx.x;  // 65536
    int b = t & 63, h = t >> 6;
    float g[4];
#pragma unroll
    for (int q = 0; q < 4; ++q) {
        int r = h + q * H;
        float a = b_ih[r] + b_hh[r];
#pragma unroll
        for (int ks = 0; ks < 4; ++ks) a += gpart[(size_t)ks * (G4 * B) + r * B + b];
        g[q] = a;
    }
    float ig = 1.f / (1.f + expf(-g[0]));
    float fg = 1.f / (1.f + expf(-g[1]));
    float gg = tanhf(g[2]);
    float og = 1.f / (1.f + expf(-g[3]));
    float c = fg * prev_c[b * H + h] + ig * gg;
    float hd = og * tanhf(c);
    cell_out[b * H + h] = c;
    hidden_out[b * H + h] = hd;
    hT[h * B + b] = hd;
}

// ---------------- K7: logits GEMM (M=32000, N=64, K=1024), LDS-tiled --------
// out[b][v] = sum_k hidden[b][k] * out_W[v][k] + out_b[v]  (raw logits)
__global__ __launch_bounds__(256) void logits_gemm(const float* __restrict__ W,
                                                   const float* __restrict__ ob,
                                                   const float* __restrict__ hT,
                                                   float* __restrict__ outl) {
    __shared__ float Wt[64][68];   // [v][k], pad 68 to spread banks
    __shared__ float Ht[64][68];   // [k][b]
    int t = threadIdx.x;
    int v0 = blockIdx.x * 64;
    int r0 = (t >> 4) * 4;         // v sub-tile
    int c0 = (t & 15) * 4;         // b sub-tile
    int sv = t >> 4;               // staging row (0..15)
    int sk = (t & 15) * 4;         // staging col chunk
    float acc[4][4] = {{0.f}};
    for (int kt = 0; kt < 16; ++kt) {
        int kb = kt * 64;
        __syncthreads();
#pragma unroll
        for (int g = 0; g < 4; ++g) {
            int vv = sv + g * 16;
            *(float4*)&Wt[vv][sk] = *(const float4*)(W + (size_t)(v0 + vv) * H + kb + sk);
            *(float4*)&Ht[vv][sk] = *(const float4*)(hT + (size_t)(kb + vv) * B + sk);
        }
        __syncthreads();
#pragma unroll
        for (int k0 = 0; k0 < 64; k0 += 4) {
            float w[4][4], h[4][4];
#pragma unroll
            for (int ri = 0; ri < 4; ++ri) *(float4*)w[ri] = *(const float4*)&Wt[r0 + ri][k0];
#pragma unroll
            for (int kj = 0; kj < 4; ++kj) *(float4*)h[kj] = *(const float4*)&Ht[k0 + kj][c0];
#pragma unroll
            for (int kj = 0; kj < 4; ++kj)
#pragma unroll
                for (int ri = 0; ri < 4; ++ri)
#pragma unroll
                    for (int ci = 0; ci < 4; ++ci)
                        acc[ri][ci] += w[ri][kj] * h[kj][ci];
        }
    }
#pragma unroll
    for (int ri = 0; ri < 4; ++ri) {
        float bias = ob[v0 + r0 + ri];
#pragma unroll
        for (int ci = 0; ci < 4; ++ci) acc[ri][ci] += bias;
    }
    // store: per ci, float4 over consecutive v
#pragma unroll
    for (int ci = 0; ci < 4; ++ci) {
        float4 o4 = make_float4(acc[0][ci], acc[1][ci], acc[2][ci], acc[3][ci]);
        *(float4*)(outl + (size_t)(c0 + ci) * V + v0 + r0) = o4;
    }
}

// ---------------- K8a: per-row logsumexp over V (coalesced [b][V] reads) ----
__global__ __launch_bounds__(256) void lse_kernel(const float* __restrict__ lg,
                                                  float* __restrict__ c) {
    __shared__ float rm[256], rl[256];
    int b = blockIdx.x, t = threadIdx.x;
    const float4* row = (const float4*)(lg + (size_t)b * V);
    float m = -3.4e38f, l = 0.f;
    for (int i = t; i < V / 4; i += 256) {
        float4 x = row[i];
        float xm = fmaxf(fmaxf(x.x, x.y), fmaxf(x.z, x.w));
        float nm = fmaxf(m, xm);
        l = l * expf(m - nm) + expf(x.x - nm) + expf(x.y - nm) + expf(x.z - nm) + expf(x.w - nm);
        m = nm;
    }
    rm[t] = m; rl[t] = l; __syncthreads();
    for (int s2 = 128; s2; s2 >>= 1) {
        if (t < s2) {
            float m2 = rm[t + s2], l2 = rl[t + s2];
            float nm = fmaxf(rm[t], m2);
            rl[t] = rl[t] * expf(rm[t] - nm) + l2 * expf(m2 - nm);
            rm[t] = nm;
        }
        __syncthreads();
    }
    if (t == 0) c[b] = rm[0] + logf(rl[0]);
}

// ---------------- K8b: in-place log_softmax subtract ------------------------
__global__ __launch_bounds__(256) void lsub_kernel(const float* __restrict__ c,
                                                   float* __restrict__ lg) {
    int g = blockIdx.x * 256 + threadIdx.x;   // 512000 float4s
    int b = g / (V / 4), w = g - b * (V / 4);
    float4* p = (float4*)(lg + (size_t)b * V) + w;
    float4 x = *p;
    float cc = c[b];
    x.x -= cc; x.y -= cc; x.z -= cc; x.w -= cc;
    *p = x;
}

// ---------------- launch ----------------------------------------------------
extern "C" void kernel_launch(void* const* d_in, const int* in_sizes, int n_in,
                              void* d_out, int out_size, void* d_ws, size_t ws_size,
                              hipStream_t stream) {
    const int*   ib      = (const int*)d_in[0];
    const float* prev_h  = (const float*)d_in[1];
    const float* prev_c  = (const float*)d_in[2];
    const float* enc     = (const float*)d_in[3];
    const float* emb_W   = (const float*)d_in[4];
    const float* attn_W  = (const float*)d_in[5];
    const float* attn_b  = (const float*)d_in[6];
    const float* W_ih    = (const float*)d_in[7];
    const float* W_hh    = (const float*)d_in[8];
    const float* b_ih    = (const float*)d_in[9];
    const float* b_hh    = (const float*)d_in[10];
    const float* out_W   = (const float*)d_in[11];
    const float* out_b   = (const float*)d_in[12];

    float* ws = (float*)d_ws;
    float* sc  = ws;                     // 131072  scores
    float* hwh = ws + 131072;            // 64
    float* xT  = ws + 131200;            // 163840  x_cat transposed [KC][B]
    float* gp  = ws + 295040;            // 1048576 gates partials [4][G4][B]
    float* cp  = ws + 1343616;           // 2097152 context partials [32][B][H]
    float* hT  = ws + 3440768;           // 65536   hidden transposed [H][B]
    float* cvec = cp;                    // 64 logsumexp constants (cp dead after K4)

    float* out    = (float*)d_out;
    float* out_ls = out;                         // (B,V)
    float* out_h  = out + (size_t)B * V;         // (B,H)
    float* out_c  = out_h + (size_t)B * H;       // (B,H)
    float* out_a  = out_c + (size_t)B * H;       // (B,S)

    hipLaunchKernelGGL(hwh_kernel,        dim3(B),      dim3(256),  0, stream, prev_h, attn_W, hwh);
    hipLaunchKernelGGL(xfill_kernel,      dim3(384),    dim3(256),  0, stream, ib, emb_W, prev_h, xT);
    hipLaunchKernelGGL(scores_kernel,     dim3(32768),  dim3(256),  0, stream, enc, attn_W, attn_b, hwh, sc);
    hipLaunchKernelGGL(softmax_kernel,    dim3(B),      dim3(256),  0, stream, sc, out_a);
    hipLaunchKernelGGL(ctx_partial_kernel,dim3(2048),   dim3(256),  0, stream, enc, out_a, cp);
    hipLaunchKernelGGL(ctx_reduce_kernel, dim3(256),    dim3(256),  0, stream, cp, xT);
    hipLaunchKernelGGL(gates_partial_kernel, dim3(512), dim3(256),  0, stream, W_ih, W_hh, xT, gp);
    hipLaunchKernelGGL(lstm_kernel,       dim3(256),    dim3(256),  0, stream, gp, b_ih, b_hh, prev_c, out_h, out_c, hT);
    hipLaunchKernelGGL(logits_gemm,       dim3(500),    dim3(256),  0, stream, out_W, out_b, hT, out_ls);
    hipLaunchKernelGGL(lse_kernel,        dim3(B),      dim3(256),  0, stream, out_ls, cvec);
    hipLaunchKernelGGL(lsub_kernel,       dim3(2000),   dim3(256),  0, stream, cvec, out_ls);
}

// Round 3
// 268.329 us; speedup vs baseline: 3.3289x; 2.0776x over previous
//
#include <hip/hip_runtime.h>
#include <math.h>

// Problem constants
#define B 64
#define S 2048
#define H 1024
#define E 512
#define V 32000
#define G4 4096        // 4*H
#define KX 1536        // E+H
#define KC 2560        // E+H+H

// ---------------- K0a: hwh[b] = dot(prev_h[b,:], attn_W[0:H]) ----------------
__global__ __launch_bounds__(256) void hwh_kernel(const float* __restrict__ prev_h,
                                                  const float* __restrict__ attn_W,
                                                  float* __restrict__ hwh) {
    __shared__ float red[256];
    int b = blockIdx.x, t = threadIdx.x;
    float4 p = *(const float4*)(prev_h + b * H + t * 4);
    float4 w = *(const float4*)(attn_W + t * 4);
    red[t] = p.x * w.x + p.y * w.y + p.z * w.z + p.w * w.w;
    __syncthreads();
    for (int s2 = 128; s2; s2 >>= 1) {
        if (t < s2) red[t] += red[t + s2];
        __syncthreads();
    }
    if (t == 0) hwh[b] = red[0];
}

// ---------------- K0b: fill xT (transposed x_cat) with emb and prev_h -------
__global__ __launch_bounds__(256) void xfill_kernel(const int* __restrict__ ib,
                                                    const float* __restrict__ emb_W,
                                                    const float* __restrict__ prev_h,
                                                    float* __restrict__ xT) {
    int t = blockIdx.x * 256 + threadIdx.x;   // 98304 threads
    if (t < E * B) {
        int b = t & 63, k = t >> 6;
        xT[k * B + b] = emb_W[(size_t)ib[b] * E + k];
    } else {
        int t2 = t - E * B;
        int b = t2 & 63, k = t2 >> 6;        // k in [0,H)
        xT[(KX + k) * B + b] = prev_h[b * H + k];
    }
}

// ---------------- K1: fused flash attention over enc (single enc pass) ------
// Block = (b, chunk of 64 s). 4 waves, 16 s each. Per s: score = enc·We + hwh
// + attn_b, online softmax, ctx += w*enc (row held in regs). Writes raw score,
// and per-block partial (M, L, ctx[H]).
__global__ __launch_bounds__(256) void fused_attn_kernel(const float* __restrict__ enc,
                                                         const float* __restrict__ attn_W,
                                                         const float* __restrict__ attn_b,
                                                         const float* __restrict__ hwh,
                                                         float* __restrict__ scores,
                                                         float* __restrict__ cpart,
                                                         float* __restrict__ mlc) {
    __shared__ float mw[4], lw[4];
    __shared__ float cbuf[4][1024];
    int t = threadIdx.x;
    int lane = t & 63, wid = t >> 6;
    int bx = blockIdx.x;
    int b = bx >> 5, chunk = bx & 31;
    int s0 = chunk * 64 + wid * 16;

    const float* We = attn_W + H;
    float4 we4[4];
#pragma unroll
    for (int c = 0; c < 4; ++c) we4[c] = *(const float4*)(We + c * 256 + lane * 4);
    float cst = hwh[b] + attn_b[0];

    float m = -INFINITY, l = 0.f;
    float4 ctx4[4] = {{0,0,0,0},{0,0,0,0},{0,0,0,0},{0,0,0,0}};

    // prefetch first row
    const float* rowp = enc + (size_t)s0 * (B * H) + b * H + lane * 4;
    float4 e4[4];
#pragma unroll
    for (int c = 0; c < 4; ++c) e4[c] = *(const float4*)(rowp + c * 256);

    for (int i = 0; i < 16; ++i) {
        float4 cur[4];
#pragma unroll
        for (int c = 0; c < 4; ++c) cur[c] = e4[c];
        if (i < 15) {
            const float* np = rowp + (size_t)(i + 1) * (B * H);
#pragma unroll
            for (int c = 0; c < 4; ++c) e4[c] = *(const float4*)(np + c * 256);
        }
        float acc = 0.f;
#pragma unroll
        for (int c = 0; c < 4; ++c)
            acc += cur[c].x * we4[c].x + cur[c].y * we4[c].y +
                   cur[c].z * we4[c].z + cur[c].w * we4[c].w;
#pragma unroll
        for (int x = 32; x; x >>= 1) acc += __shfl_xor(acc, x);
        float score = acc + cst;
        if (lane == 0) scores[b * S + s0 + i] = score;
        float nm = fmaxf(m, score);
        float sc = expf(m - nm);
        float w = expf(score - nm);
        l = l * sc + w;
        m = nm;
#pragma unroll
        for (int c = 0; c < 4; ++c) {
            ctx4[c].x = ctx4[c].x * sc + w * cur[c].x;
            ctx4[c].y = ctx4[c].y * sc + w * cur[c].y;
            ctx4[c].z = ctx4[c].z * sc + w * cur[c].z;
            ctx4[c].w = ctx4[c].w * sc + w * cur[c].w;
        }
    }

    if (lane == 0) { mw[wid] = m; lw[wid] = l; }
    __syncthreads();
    float M = fmaxf(fmaxf(mw[0], mw[1]), fmaxf(mw[2], mw[3]));
    float L = lw[0] * expf(mw[0] - M) + lw[1] * expf(mw[1] - M) +
              lw[2] * expf(mw[2] - M) + lw[3] * expf(mw[3] - M);
    float msc = expf(m - M);
#pragma unroll
    for (int c = 0; c < 4; ++c) {
        float4 v = ctx4[c];
        v.x *= msc; v.y *= msc; v.z *= msc; v.w *= msc;
        *(float4*)&cbuf[wid][c * 256 + lane * 4] = v;
    }
    __syncthreads();
    if (wid == 0) {
#pragma unroll
        for (int c = 0; c < 4; ++c) {
            int h = c * 256 + lane * 4;
            float4 a0 = *(float4*)&cbuf[0][h];
            float4 a1 = *(float4*)&cbuf[1][h];
            float4 a2 = *(float4*)&cbuf[2][h];
            float4 a3 = *(float4*)&cbuf[3][h];
            float4 s4 = make_float4(a0.x + a1.x + a2.x + a3.x,
                                    a0.y + a1.y + a2.y + a3.y,
                                    a0.z + a1.z + a2.z + a3.z,
                                    a0.w + a1.w + a2.w + a3.w);
            *(float4*)(cpart + (size_t)(chunk * B + b) * H + h) = s4;
        }
    }
    if (t == 0) {
        mlc[(b * 32 + chunk) * 2] = M;
        mlc[(b * 32 + chunk) * 2 + 1] = L;
    }
}

// ---------------- K2: merge chunk partials -> context (into xT) + final M,L -
__global__ __launch_bounds__(256) void attn_reduce_kernel(const float* __restrict__ cpart,
                                                          const float* __restrict__ mlc,
                                                          float* __restrict__ xT,
                                                          float* __restrict__ mlf) {
    __shared__ float Ms[32], Ls[32];
    int b = blockIdx.x, t = threadIdx.x;
    if (t < 32) {
        Ms[t] = mlc[(b * 32 + t) * 2];
        Ls[t] = mlc[(b * 32 + t) * 2 + 1];
    }
    __syncthreads();
    float Mg = -INFINITY;
#pragma unroll
    for (int c = 0; c < 32; ++c) Mg = fmaxf(Mg, Ms[c]);
    float Lg = 0.f;
#pragma unroll
    for (int c = 0; c < 32; ++c) Lg += Ls[c] * expf(Ms[c] - Mg);
    float inv = 1.f / Lg;
    int h = t * 4;
    float4 acc = {0, 0, 0, 0};
    for (int c = 0; c < 32; ++c) {
        float w = expf(Ms[c] - Mg);
        float4 v = *(const float4*)(cpart + (size_t)(c * B + b) * H + h);
        acc.x += w * v.x; acc.y += w * v.y; acc.z += w * v.z; acc.w += w * v.w;
    }
    xT[(E + h) * B + b]     = acc.x * inv;
    xT[(E + h + 1) * B + b] = acc.y * inv;
    xT[(E + h + 2) * B + b] = acc.z * inv;
    xT[(E + h + 3) * B + b] = acc.w * inv;
    if (t == 0) { mlf[b * 2] = Mg; mlf[b * 2 + 1] = Lg; }
}

// ---------------- K3: attn_weights[b,s] = exp(score - Mg)/Lg ----------------
__global__ __launch_bounds__(256) void attn_weights_kernel(const float* __restrict__ scores,
                                                           const float* __restrict__ mlf,
                                                           float* __restrict__ attn) {
    int g = blockIdx.x * 256 + threadIdx.x;  // 131072
    int b = g >> 11;
    float Mg = mlf[b * 2], inv = 1.f / mlf[b * 2 + 1];
    attn[g] = expf(scores[g] - Mg) * inv;
}

// ---------------- K4: gates GEMM (M=4096, N=64, K=2560 in 4 chunks) ---------
// gpart[ks][r][b] partial over k-chunk ks. LDS-tiled 64x64, 4x4 per thread.
__global__ __launch_bounds__(256) void gates_gemm(const float* __restrict__ W_ih,
                                                  const float* __restrict__ W_hh,
                                                  const float* __restrict__ xT,
                                                  float* __restrict__ gpart) {
    __shared__ float Wt[64][68];
    __shared__ float Xt[64][68];
    int t = threadIdx.x;
    int rtile = blockIdx.x >> 2, ks = blockIdx.x & 3;
    int r0 = rtile * 64;
    int rr0 = (t >> 4) * 4;
    int c0 = (t & 15) * 4;
    int sv = t >> 4;
    int sk = (t & 15) * 4;
    float acc[4][4] = {{0.f}};
    for (int kt = 0; kt < 10; ++kt) {
        int kb = ks * 640 + kt * 64;
        const float* wbase;
        int wstride;
        if (kb < KX) { wbase = W_ih + kb; wstride = KX; }
        else         { wbase = W_hh + (kb - KX); wstride = H; }
        __syncthreads();
#pragma unroll
        for (int g = 0; g < 4; ++g) {
            int vv = sv + g * 16;
            *(float4*)&Wt[vv][sk] = *(const float4*)(wbase + (size_t)(r0 + vv) * wstride + sk);
            *(float4*)&Xt[vv][sk] = *(const float4*)(xT + (size_t)(kb + vv) * B + sk);
        }
        __syncthreads();
#pragma unroll
        for (int k0 = 0; k0 < 64; k0 += 4) {
            float w[4][4], x[4][4];
#pragma unroll
            for (int ri = 0; ri < 4; ++ri) *(float4*)w[ri] = *(const float4*)&Wt[rr0 + ri][k0];
#pragma unroll
            for (int kj = 0; kj < 4; ++kj) *(float4*)x[kj] = *(const float4*)&Xt[k0 + kj][c0];
#pragma unroll
            for (int kj = 0; kj < 4; ++kj)
#pragma unroll
                for (int ri = 0; ri < 4; ++ri)
#pragma unroll
                    for (int ci = 0; ci < 4; ++ci)
                        acc[ri][ci] += w[ri][kj] * x[kj][ci];
        }
    }
#pragma unroll
    for (int ri = 0; ri < 4; ++ri) {
        float4 o4 = make_float4(acc[ri][0], acc[ri][1], acc[ri][2], acc[ri][3]);
        *(float4*)(gpart + (size_t)ks * (G4 * B) + (size_t)(r0 + rr0 + ri) * B + c0) = o4;
    }
}

// ---------------- K5: LSTM elementwise --------------------------------------
__global__ __launch_bounds__(256) void lstm_kernel(const float* __restrict__ gpart,
                                                   const float* __restrict__ b_ih,
                                                   const float* __restrict__ b_hh,
                                                   const float* __restrict__ prev_c,
                                                   float* __restrict__ hidden_out,
                                                   float* __restrict__ cell_out,
                                                   float* __restrict__ hT) {
    int t = blockIdx.x * 256 + threadIdx.x;  // 65536
    int b = t & 63, h = t >> 6;
    float g[4];
#pragma unroll
    for (int q = 0; q < 4; ++q) {
        int r = h + q * H;
        float a = b_ih[r] + b_hh[r];
#pragma unroll
        for (int ks = 0; ks < 4; ++ks) a += gpart[(size_t)ks * (G4 * B) + r * B + b];
        g[q] = a;
    }
    float ig = 1.f / (1.f + expf(-g[0]));
    float fg = 1.f / (1.f + expf(-g[1]));
    float gg = tanhf(g[2]);
    float og = 1.f / (1.f + expf(-g[3]));
    float c = fg * prev_c[b * H + h] + ig * gg;
    float hd = og * tanhf(c);
    cell_out[b * H + h] = c;
    hidden_out[b * H + h] = hd;
    hT[h * B + b] = hd;
}

// ---------------- K6: logits GEMM (M=32000, N=64, K=1024), LDS-tiled --------
__global__ __launch_bounds__(256) void logits_gemm(const float* __restrict__ W,
                                                   const float* __restrict__ ob,
                                                   const float* __restrict__ hT,
                                                   float* __restrict__ outl) {
    __shared__ float Wt[64][68];
    __shared__ float Ht[64][68];
    int t = threadIdx.x;
    int v0 = blockIdx.x * 64;
    int r0 = (t >> 4) * 4;
    int c0 = (t & 15) * 4;
    int sv = t >> 4;
    int sk = (t & 15) * 4;
    float acc[4][4] = {{0.f}};
    for (int kt = 0; kt < 16; ++kt) {
        int kb = kt * 64;
        __syncthreads();
#pragma unroll
        for (int g = 0; g < 4; ++g) {
            int vv = sv + g * 16;
            *(float4*)&Wt[vv][sk] = *(const float4*)(W + (size_t)(v0 + vv) * H + kb + sk);
            *(float4*)&Ht[vv][sk] = *(const float4*)(hT + (size_t)(kb + vv) * B + sk);
        }
        __syncthreads();
#pragma unroll
        for (int k0 = 0; k0 < 64; k0 += 4) {
            float w[4][4], h[4][4];
#pragma unroll
            for (int ri = 0; ri < 4; ++ri) *(float4*)w[ri] = *(const float4*)&Wt[r0 + ri][k0];
#pragma unroll
            for (int kj = 0; kj < 4; ++kj) *(float4*)h[kj] = *(const float4*)&Ht[k0 + kj][c0];
#pragma unroll
            for (int kj = 0; kj < 4; ++kj)
#pragma unroll
                for (int ri = 0; ri < 4; ++ri)
#pragma unroll
                    for (int ci = 0; ci < 4; ++ci)
                        acc[ri][ci] += w[ri][kj] * h[kj][ci];
        }
    }
#pragma unroll
    for (int ri = 0; ri < 4; ++ri) {
        float bias = ob[v0 + r0 + ri];
#pragma unroll
        for (int ci = 0; ci < 4; ++ci) acc[ri][ci] += bias;
    }
#pragma unroll
    for (int ci = 0; ci < 4; ++ci) {
        float4 o4 = make_float4(acc[0][ci], acc[1][ci], acc[2][ci], acc[3][ci]);
        *(float4*)(outl + (size_t)(c0 + ci) * V + v0 + r0) = o4;
    }
}

// ---------------- K7a: per-row logsumexp over V -----------------------------
__global__ __launch_bounds__(256) void lse_kernel(const float* __restrict__ lg,
                                                  float* __restrict__ c) {
    __shared__ float rm[256], rl[256];
    int b = blockIdx.x, t = threadIdx.x;
    const float4* row = (const float4*)(lg + (size_t)b * V);
    float m = -3.4e38f, l = 0.f;
    for (int i = t; i < V / 4; i += 256) {
        float4 x = row[i];
        float xm = fmaxf(fmaxf(x.x, x.y), fmaxf(x.z, x.w));
        float nm = fmaxf(m, xm);
        l = l * expf(m - nm) + expf(x.x - nm) + expf(x.y - nm) + expf(x.z - nm) + expf(x.w - nm);
        m = nm;
    }
    rm[t] = m; rl[t] = l; __syncthreads();
    for (int s2 = 128; s2; s2 >>= 1) {
        if (t < s2) {
            float m2 = rm[t + s2], l2 = rl[t + s2];
            float nm = fmaxf(rm[t], m2);
            rl[t] = rl[t] * expf(rm[t] - nm) + l2 * expf(m2 - nm);
            rm[t] = nm;
        }
        __syncthreads();
    }
    if (t == 0) c[b] = rm[0] + logf(rl[0]);
}

// ---------------- K7b: in-place log_softmax subtract ------------------------
__global__ __launch_bounds__(256) void lsub_kernel(const float* __restrict__ c,
                                                   float* __restrict__ lg) {
    int g = blockIdx.x * 256 + threadIdx.x;   // 512000 float4s
    int b = g / (V / 4), w = g - b * (V / 4);
    float4* p = (float4*)(lg + (size_t)b * V) + w;
    float4 x = *p;
    float cc = c[b];
    x.x -= cc; x.y -= cc; x.z -= cc; x.w -= cc;
    *p = x;
}

// ---------------- launch ----------------------------------------------------
extern "C" void kernel_launch(void* const* d_in, const int* in_sizes, int n_in,
                              void* d_out, int out_size, void* d_ws, size_t ws_size,
                              hipStream_t stream) {
    const int*   ib      = (const int*)d_in[0];
    const float* prev_h  = (const float*)d_in[1];
    const float* prev_c  = (const float*)d_in[2];
    const float* enc     = (const float*)d_in[3];
    const float* emb_W   = (const float*)d_in[4];
    const float* attn_W  = (const float*)d_in[5];
    const float* attn_b  = (const float*)d_in[6];
    const float* W_ih    = (const float*)d_in[7];
    const float* W_hh    = (const float*)d_in[8];
    const float* b_ih    = (const float*)d_in[9];
    const float* b_hh    = (const float*)d_in[10];
    const float* out_b   = (const float*)d_in[12];
    const float* out_W   = (const float*)d_in[11];

    float* ws = (float*)d_ws;
    float* sc  = ws;                     // 131072  scores (B*S)
    float* hwh = ws + 131072;            // 64
    float* xT  = ws + 131200;            // 163840  x_cat transposed [KC][B]
    float* gp  = ws + 295040;            // 1048576 gates partials [4][G4][B]
    float* cp  = ws + 1343616;           // 2097152 context partials [32][B][H]
    float* mlc = ws + 3440768;           // 4096    per-chunk (M,L)
    float* mlf = ws + 3444864;           // 128     per-b final (M,L)
    float* hT  = ws + 3444992;           // 65536   hidden transposed [H][B]
    float* cvec = cp;                    // 64 logsumexp constants (cp dead)

    float* out    = (float*)d_out;
    float* out_ls = out;                         // (B,V)
    float* out_h  = out + (size_t)B * V;         // (B,H)
    float* out_c  = out_h + (size_t)B * H;       // (B,H)
    float* out_a  = out_c + (size_t)B * H;       // (B,S)

    hipLaunchKernelGGL(hwh_kernel,          dim3(B),     dim3(256), 0, stream, prev_h, attn_W, hwh);
    hipLaunchKernelGGL(xfill_kernel,        dim3(384),   dim3(256), 0, stream, ib, emb_W, prev_h, xT);
    hipLaunchKernelGGL(fused_attn_kernel,   dim3(2048),  dim3(256), 0, stream, enc, attn_W, attn_b, hwh, sc, cp, mlc);
    hipLaunchKernelGGL(attn_reduce_kernel,  dim3(B),     dim3(256), 0, stream, cp, mlc, xT, mlf);
    hipLaunchKernelGGL(attn_weights_kernel, dim3(512),   dim3(256), 0, stream, sc, mlf, out_a);
    hipLaunchKernelGGL(gates_gemm,          dim3(256),   dim3(256), 0, stream, W_ih, W_hh, xT, gp);
    hipLaunchKernelGGL(lstm_kernel,         dim3(256),   dim3(256), 0, stream, gp, b_ih, b_hh, prev_c, out_h, out_c, hT);
    hipLaunchKernelGGL(logits_gemm,         dim3(500),   dim3(256), 0, stream, out_W, out_b, hT, out_ls);
    hipLaunchKernelGGL(lse_kernel,          dim3(B),     dim3(256), 0, stream, out_ls, cvec);
    hipLaunchKernelGGL(lsub_kernel,         dim3(2000),  dim3(256), 0, stream, cvec, out_ls);
}

// Round 4
// 208.218 us; speedup vs baseline: 4.2899x; 1.2887x over previous
//
#include <hip/hip_runtime.h>
#include <math.h>

// Problem constants
#define B 64
#define S 2048
#define H 1024
#define E 512
#define V 32000
#define G4 4096        // 4*H
#define KX 1536        // E+H
#define KC 2560        // E+H+H

typedef __attribute__((ext_vector_type(8))) short short8v;
typedef __attribute__((ext_vector_type(4))) float f32x4;

__device__ __forceinline__ ushort f2bf(float f) {
    union { float f; unsigned u; } v; v.f = f;
    unsigned r = v.u + 0x7FFFu + ((v.u >> 16) & 1u);
    return (ushort)(r >> 16);
}

// ---------------- K0: prep = hwh (blocks 0..63) + xfill (blocks 64..447) ----
__global__ __launch_bounds__(256) void prep_kernel(const int* __restrict__ ib,
                                                   const float* __restrict__ emb_W,
                                                   const float* __restrict__ prev_h,
                                                   const float* __restrict__ attn_W,
                                                   float* __restrict__ hwh,
                                                   float* __restrict__ xT) {
    __shared__ float red[256];
    int t = threadIdx.x;
    if (blockIdx.x < 64) {
        int b = blockIdx.x;
        float4 p = *(const float4*)(prev_h + b * H + t * 4);
        float4 w = *(const float4*)(attn_W + t * 4);
        red[t] = p.x * w.x + p.y * w.y + p.z * w.z + p.w * w.w;
        __syncthreads();
        for (int s2 = 128; s2; s2 >>= 1) {
            if (t < s2) red[t] += red[t + s2];
            __syncthreads();
        }
        if (t == 0) hwh[b] = red[0];
    } else {
        int g = (blockIdx.x - 64) * 256 + t;   // 98304 threads
        if (g < E * B) {
            int b = g & 63, k = g >> 6;
            xT[k * B + b] = emb_W[(size_t)ib[b] * E + k];
        } else {
            int g2 = g - E * B;
            int b = g2 & 63, k = g2 >> 6;      // k in [0,H)
            xT[(KX + k) * B + b] = prev_h[b * H + k];
        }
    }
}

// ---------------- K1: fused flash attention over enc (single enc pass) ------
__global__ __launch_bounds__(256) void fused_attn_kernel(const float* __restrict__ enc,
                                                         const float* __restrict__ attn_W,
                                                         const float* __restrict__ attn_b,
                                                         const float* __restrict__ hwh,
                                                         float* __restrict__ scores,
                                                         float* __restrict__ cpart,
                                                         float* __restrict__ mlc) {
    __shared__ float mw[4], lw[4];
    __shared__ float cbuf[4][1024];
    int t = threadIdx.x;
    int lane = t & 63, wid = t >> 6;
    int bx = blockIdx.x;
    int b = bx >> 5, chunk = bx & 31;
    int s0 = chunk * 64 + wid * 16;

    const float* We = attn_W + H;
    float4 we4[4];
#pragma unroll
    for (int c = 0; c < 4; ++c) we4[c] = *(const float4*)(We + c * 256 + lane * 4);
    float cst = hwh[b] + attn_b[0];

    float m = -INFINITY, l = 0.f;
    float4 ctx4[4] = {{0,0,0,0},{0,0,0,0},{0,0,0,0},{0,0,0,0}};

    const float* rowp = enc + (size_t)s0 * (B * H) + b * H + lane * 4;
    float4 e4[4];
#pragma unroll
    for (int c = 0; c < 4; ++c) e4[c] = *(const float4*)(rowp + c * 256);

    for (int i = 0; i < 16; ++i) {
        float4 cur[4];
#pragma unroll
        for (int c = 0; c < 4; ++c) cur[c] = e4[c];
        if (i < 15) {
            const float* np = rowp + (size_t)(i + 1) * (B * H);
#pragma unroll
            for (int c = 0; c < 4; ++c) e4[c] = *(const float4*)(np + c * 256);
        }
        float acc = 0.f;
#pragma unroll
        for (int c = 0; c < 4; ++c)
            acc += cur[c].x * we4[c].x + cur[c].y * we4[c].y +
                   cur[c].z * we4[c].z + cur[c].w * we4[c].w;
#pragma unroll
        for (int x = 32; x; x >>= 1) acc += __shfl_xor(acc, x);
        float score = acc + cst;
        if (lane == 0) scores[b * S + s0 + i] = score;
        float nm = fmaxf(m, score);
        float sc = expf(m - nm);
        float w = expf(score - nm);
        l = l * sc + w;
        m = nm;
#pragma unroll
        for (int c = 0; c < 4; ++c) {
            ctx4[c].x = ctx4[c].x * sc + w * cur[c].x;
            ctx4[c].y = ctx4[c].y * sc + w * cur[c].y;
            ctx4[c].z = ctx4[c].z * sc + w * cur[c].z;
            ctx4[c].w = ctx4[c].w * sc + w * cur[c].w;
        }
    }

    if (lane == 0) { mw[wid] = m; lw[wid] = l; }
    __syncthreads();
    float M = fmaxf(fmaxf(mw[0], mw[1]), fmaxf(mw[2], mw[3]));
    float L = lw[0] * expf(mw[0] - M) + lw[1] * expf(mw[1] - M) +
              lw[2] * expf(mw[2] - M) + lw[3] * expf(mw[3] - M);
    float msc = expf(m - M);
#pragma unroll
    for (int c = 0; c < 4; ++c) {
        float4 v = ctx4[c];
        v.x *= msc; v.y *= msc; v.z *= msc; v.w *= msc;
        *(float4*)&cbuf[wid][c * 256 + lane * 4] = v;
    }
    __syncthreads();
    if (wid == 0) {
#pragma unroll
        for (int c = 0; c < 4; ++c) {
            int h = c * 256 + lane * 4;
            float4 a0 = *(float4*)&cbuf[0][h];
            float4 a1 = *(float4*)&cbuf[1][h];
            float4 a2 = *(float4*)&cbuf[2][h];
            float4 a3 = *(float4*)&cbuf[3][h];
            float4 s4 = make_float4(a0.x + a1.x + a2.x + a3.x,
                                    a0.y + a1.y + a2.y + a3.y,
                                    a0.z + a1.z + a2.z + a3.z,
                                    a0.w + a1.w + a2.w + a3.w);
            *(float4*)(cpart + (size_t)(chunk * B + b) * H + h) = s4;
        }
    }
    if (t == 0) {
        mlc[(b * 32 + chunk) * 2] = M;
        mlc[(b * 32 + chunk) * 2 + 1] = L;
    }
}

// ---------------- K2: merge partials -> context + final M,L + attn weights --
__global__ __launch_bounds__(256) void attn_reduce_kernel(const float* __restrict__ cpart,
                                                          const float* __restrict__ mlc,
                                                          const float* __restrict__ scores,
                                                          float* __restrict__ xT,
                                                          float* __restrict__ mlf,
                                                          float* __restrict__ attn) {
    __shared__ float Ms[32], Ls[32];
    int b = blockIdx.x, t = threadIdx.x;
    if (t < 32) {
        Ms[t] = mlc[(b * 32 + t) * 2];
        Ls[t] = mlc[(b * 32 + t) * 2 + 1];
    }
    __syncthreads();
    float Mg = -INFINITY;
#pragma unroll
    for (int c = 0; c < 32; ++c) Mg = fmaxf(Mg, Ms[c]);
    float Lg = 0.f;
#pragma unroll
    for (int c = 0; c < 32; ++c) Lg += Ls[c] * expf(Ms[c] - Mg);
    float inv = 1.f / Lg;
    int h = t * 4;
    float4 acc = {0, 0, 0, 0};
    for (int c = 0; c < 32; ++c) {
        float w = expf(Ms[c] - Mg);
        float4 v = *(const float4*)(cpart + (size_t)(c * B + b) * H + h);
        acc.x += w * v.x; acc.y += w * v.y; acc.z += w * v.z; acc.w += w * v.w;
    }
    xT[(E + h) * B + b]     = acc.x * inv;
    xT[(E + h + 1) * B + b] = acc.y * inv;
    xT[(E + h + 2) * B + b] = acc.z * inv;
    xT[(E + h + 3) * B + b] = acc.w * inv;
    if (t == 0) { mlf[b * 2] = Mg; mlf[b * 2 + 1] = Lg; }
    // attn weights for this row
#pragma unroll
    for (int i = 0; i < 8; ++i) {
        int s = t + i * 256;
        attn[b * S + s] = expf(scores[b * S + s] - Mg) * inv;
    }
}

// ---------------- K3: gates GEMM (M=4096, N=64, K=2560 in 8 chunks) ---------
__global__ __launch_bounds__(256) void gates_gemm(const float* __restrict__ W_ih,
                                                  const float* __restrict__ W_hh,
                                                  const float* __restrict__ xT,
                                                  float* __restrict__ gpart) {
    __shared__ float Wt[64][68];
    __shared__ float Xt[64][68];
    int t = threadIdx.x;
    int rtile = blockIdx.x >> 3, ks = blockIdx.x & 7;   // 512 blocks
    int r0 = rtile * 64;
    int rr0 = (t >> 4) * 4;
    int c0 = (t & 15) * 4;
    int sv = t >> 4;
    int sk = (t & 15) * 4;
    float acc[4][4] = {{0.f}};
    for (int kt = 0; kt < 5; ++kt) {
        int kb = ks * 320 + kt * 64;
        const float* wbase;
        int wstride;
        if (kb < KX) { wbase = W_ih + kb; wstride = KX; }
        else         { wbase = W_hh + (kb - KX); wstride = H; }
        __syncthreads();
#pragma unroll
        for (int g = 0; g < 4; ++g) {
            int vv = sv + g * 16;
            *(float4*)&Wt[vv][sk] = *(const float4*)(wbase + (size_t)(r0 + vv) * wstride + sk);
            *(float4*)&Xt[vv][sk] = *(const float4*)(xT + (size_t)(kb + vv) * B + sk);
        }
        __syncthreads();
#pragma unroll
        for (int k0 = 0; k0 < 64; k0 += 4) {
            float w[4][4], x[4][4];
#pragma unroll
            for (int ri = 0; ri < 4; ++ri) *(float4*)w[ri] = *(const float4*)&Wt[rr0 + ri][k0];
#pragma unroll
            for (int kj = 0; kj < 4; ++kj) *(float4*)x[kj] = *(const float4*)&Xt[k0 + kj][c0];
#pragma unroll
            for (int kj = 0; kj < 4; ++kj)
#pragma unroll
                for (int ri = 0; ri < 4; ++ri)
#pragma unroll
                    for (int ci = 0; ci < 4; ++ci)
                        acc[ri][ci] += w[ri][kj] * x[kj][ci];
        }
    }
#pragma unroll
    for (int ri = 0; ri < 4; ++ri) {
        float4 o4 = make_float4(acc[ri][0], acc[ri][1], acc[ri][2], acc[ri][3]);
        *(float4*)(gpart + (size_t)ks * (G4 * B) + (size_t)(r0 + rr0 + ri) * B + c0) = o4;
    }
}

// ---------------- K4: LSTM elementwise (8 partials, emits bf16 hb[b][k]) ----
__global__ __launch_bounds__(256) void lstm_kernel(const float* __restrict__ gpart,
                                                   const float* __restrict__ b_ih,
                                                   const float* __restrict__ b_hh,
                                                   const float* __restrict__ prev_c,
                                                   float* __restrict__ hidden_out,
                                                   float* __restrict__ cell_out,
                                                   ushort* __restrict__ hb) {
    int t = blockIdx.x * 256 + threadIdx.x;  // 65536
    int b = t & 63, h = t >> 6;
    float g[4];
#pragma unroll
    for (int q = 0; q < 4; ++q) {
        int r = h + q * H;
        float a = b_ih[r] + b_hh[r];
#pragma unroll
        for (int ks = 0; ks < 8; ++ks) a += gpart[(size_t)ks * (G4 * B) + r * B + b];
        g[q] = a;
    }
    float ig = 1.f / (1.f + expf(-g[0]));
    float fg = 1.f / (1.f + expf(-g[1]));
    float gg = tanhf(g[2]);
    float og = 1.f / (1.f + expf(-g[3]));
    float c = fg * prev_c[b * H + h] + ig * gg;
    float hd = og * tanhf(c);
    cell_out[b * H + h] = c;
    hidden_out[b * H + h] = hd;
    hb[b * H + h] = f2bf(hd);
}

// ---------------- K5: logits via bf16 MFMA ----------------------------------
// C[v][b] = sum_k W[v][k]*h[b][k]; A = W (v x k) converted f32->bf16 on the
// fly, B = hb (b x k) bf16. Tile 64v x 64b x (K in 16 steps of 64).
// LDS swizzle: byte ^= (row&7)<<4 on 16B granules -> conflict-free b128 frags.
__global__ __launch_bounds__(256) void logits_mfma(const float* __restrict__ W,
                                                   const float* __restrict__ ob,
                                                   const ushort* __restrict__ hb,
                                                   float* __restrict__ outl) {
    __shared__ ushort Wt[64 * 64];   // [v][k] bf16, swizzled
    __shared__ ushort Bt[64 * 64];   // [b][k] bf16, swizzled
    __shared__ float  Ct[64][68];    // [b][v] transpose buffer
    int t = threadIdx.x;
    int lane = t & 63, wid = t >> 6;
    int v0 = blockIdx.x * 64;

    int srow = t >> 2;               // staging row 0..63
    int sq = t & 3;                  // 16-float quarter within row

    f32x4 acc[4] = {{0.f,0.f,0.f,0.f},{0.f,0.f,0.f,0.f},{0.f,0.f,0.f,0.f},{0.f,0.f,0.f,0.f}};

    int r = lane & 15, g = lane >> 4;
    int arow = wid * 16 + r;
    int aswz = (arow & 7) << 4;
    unsigned abase = arow * 128;

    for (int kt = 0; kt < 16; ++kt) {
        int k0 = kt * 64;
        __syncthreads();
        // stage W: row srow, 16 floats -> 16 bf16 (two 16B writes)
        {
            const float* src = W + (size_t)(v0 + srow) * H + k0 + sq * 16;
            float4 f0 = *(const float4*)(src + 0);
            float4 f1 = *(const float4*)(src + 4);
            float4 f2 = *(const float4*)(src + 8);
            float4 f3 = *(const float4*)(src + 12);
            short8v w0, w1;
            w0[0] = (short)f2bf(f0.x); w0[1] = (short)f2bf(f0.y);
            w0[2] = (short)f2bf(f0.z); w0[3] = (short)f2bf(f0.w);
            w0[4] = (short)f2bf(f1.x); w0[5] = (short)f2bf(f1.y);
            w0[6] = (short)f2bf(f1.z); w0[7] = (short)f2bf(f1.w);
            w1[0] = (short)f2bf(f2.x); w1[1] = (short)f2bf(f2.y);
            w1[2] = (short)f2bf(f2.z); w1[3] = (short)f2bf(f2.w);
            w1[4] = (short)f2bf(f3.x); w1[5] = (short)f2bf(f3.y);
            w1[6] = (short)f2bf(f3.z); w1[7] = (short)f2bf(f3.w);
            unsigned rb = srow * 128;
            unsigned sw = (srow & 7) << 4;
            *(short8v*)((char*)Wt + rb + ((sq * 32 + 0) ^ sw))  = w0;
            *(short8v*)((char*)Wt + rb + ((sq * 32 + 16) ^ sw)) = w1;
        }
        // stage hb: row srow (b), 16 bf16 = 32 B direct copy
        {
            const ushort* hsrc = hb + (size_t)srow * H + k0 + sq * 16;
            uint4 h0 = *(const uint4*)(hsrc);
            uint4 h1 = *(const uint4*)(hsrc + 8);
            unsigned rb = srow * 128;
            unsigned sw = (srow & 7) << 4;
            *(uint4*)((char*)Bt + rb + ((sq * 32 + 0) ^ sw))  = h0;
            *(uint4*)((char*)Bt + rb + ((sq * 32 + 16) ^ sw)) = h1;
        }
        __syncthreads();
#pragma unroll
        for (int kk = 0; kk < 2; ++kk) {
            unsigned koff = kk * 64 + g * 16;
            short8v a = *(short8v*)((char*)Wt + abase + (koff ^ aswz));
#pragma unroll
            for (int bt = 0; bt < 4; ++bt) {
                int brow = bt * 16 + r;
                short8v bb = *(short8v*)((char*)Bt + brow * 128 + (koff ^ ((brow & 7) << 4)));
                acc[bt] = __builtin_amdgcn_mfma_f32_16x16x32_bf16(a, bb, acc[bt], 0, 0, 0);
            }
        }
    }
    __syncthreads();
    // bias + transpose through LDS (C/D layout: col=lane&15, row=(lane>>4)*4+j)
    float bias[4];
#pragma unroll
    for (int j = 0; j < 4; ++j) bias[j] = ob[v0 + wid * 16 + g * 4 + j];
#pragma unroll
    for (int bt = 0; bt < 4; ++bt)
#pragma unroll
        for (int j = 0; j < 4; ++j)
            Ct[bt * 16 + r][wid * 16 + g * 4 + j] = acc[bt][j] + bias[j];
    __syncthreads();
    int ob_ = t >> 2;
    int vq = (t & 3) * 16;
#pragma unroll
    for (int c = 0; c < 4; ++c)
        *(float4*)(outl + (size_t)ob_ * V + v0 + vq + c * 4) = *(float4*)&Ct[ob_][vq + c * 4];
}

// ---------------- K6a: per-row logsumexp over V -----------------------------
__global__ __launch_bounds__(256) void lse_kernel(const float* __restrict__ lg,
                                                  float* __restrict__ c) {
    __shared__ float rm[256], rl[256];
    int b = blockIdx.x, t = threadIdx.x;
    const float4* row = (const float4*)(lg + (size_t)b * V);
    float m = -3.4e38f, l = 0.f;
    for (int i = t; i < V / 4; i += 256) {
        float4 x = row[i];
        float xm = fmaxf(fmaxf(x.x, x.y), fmaxf(x.z, x.w));
        float nm = fmaxf(m, xm);
        l = l * expf(m - nm) + expf(x.x - nm) + expf(x.y - nm) + expf(x.z - nm) + expf(x.w - nm);
        m = nm;
    }
    rm[t] = m; rl[t] = l; __syncthreads();
    for (int s2 = 128; s2; s2 >>= 1) {
        if (t < s2) {
            float m2 = rm[t + s2], l2 = rl[t + s2];
            float nm = fmaxf(rm[t], m2);
            rl[t] = rl[t] * expf(rm[t] - nm) + l2 * expf(m2 - nm);
            rm[t] = nm;
        }
        __syncthreads();
    }
    if (t == 0) c[b] = rm[0] + logf(rl[0]);
}

// ---------------- K6b: in-place log_softmax subtract ------------------------
__global__ __launch_bounds__(256) void lsub_kernel(const float* __restrict__ c,
                                                   float* __restrict__ lg) {
    int g = blockIdx.x * 256 + threadIdx.x;   // 512000 float4s
    int b = g / (V / 4), w = g - b * (V / 4);
    float4* p = (float4*)(lg + (size_t)b * V) + w;
    float4 x = *p;
    float cc = c[b];
    x.x -= cc; x.y -= cc; x.z -= cc; x.w -= cc;
    *p = x;
}

// ---------------- launch ----------------------------------------------------
extern "C" void kernel_launch(void* const* d_in, const int* in_sizes, int n_in,
                              void* d_out, int out_size, void* d_ws, size_t ws_size,
                              hipStream_t stream) {
    const int*   ib      = (const int*)d_in[0];
    const float* prev_h  = (const float*)d_in[1];
    const float* prev_c  = (const float*)d_in[2];
    const float* enc     = (const float*)d_in[3];
    const float* emb_W   = (const float*)d_in[4];
    const float* attn_W  = (const float*)d_in[5];
    const float* attn_b  = (const float*)d_in[6];
    const float* W_ih    = (const float*)d_in[7];
    const float* W_hh    = (const float*)d_in[8];
    const float* b_ih    = (const float*)d_in[9];
    const float* b_hh    = (const float*)d_in[10];
    const float* out_W   = (const float*)d_in[11];
    const float* out_b   = (const float*)d_in[12];

    float* ws = (float*)d_ws;
    // ws layout (floats), total ~9.7 MB
    float* sc   = ws;                    // 131072  scores (B*S)
    float* hwh  = ws + 131072;           // 64
    float* xT   = ws + 131200;           // 163840  [KC][B]
    float* cp   = ws + 295040;           // 2097152 ctx partials [32][B][H]
    float* gp   = cp;                    // 2097152 gates partials [8][G4][B] (cp dead)
    float* mlc  = ws + 2392192;          // 4096
    float* mlf  = ws + 2396288;          // 128
    float* cvec = ws + 2396416;          // 64
    ushort* hb  = (ushort*)(ws + 2396480); // 65536 ushorts = bf16 hidden [B][H]

    float* out    = (float*)d_out;
    float* out_ls = out;                         // (B,V)
    float* out_h  = out + (size_t)B * V;         // (B,H)
    float* out_c  = out_h + (size_t)B * H;       // (B,H)
    float* out_a  = out_c + (size_t)B * H;       // (B,S)

    hipLaunchKernelGGL(prep_kernel,        dim3(448),  dim3(256), 0, stream, ib, emb_W, prev_h, attn_W, hwh, xT);
    hipLaunchKernelGGL(fused_attn_kernel,  dim3(2048), dim3(256), 0, stream, enc, attn_W, attn_b, hwh, sc, cp, mlc);
    hipLaunchKernelGGL(attn_reduce_kernel, dim3(B),    dim3(256), 0, stream, cp, mlc, sc, xT, mlf, out_a);
    hipLaunchKernelGGL(gates_gemm,         dim3(512),  dim3(256), 0, stream, W_ih, W_hh, xT, gp);
    hipLaunchKernelGGL(lstm_kernel,        dim3(256),  dim3(256), 0, stream, gp, b_ih, b_hh, prev_c, out_h, out_c, hb);
    hipLaunchKernelGGL(logits_mfma,        dim3(500),  dim3(256), 0, stream, out_W, out_b, hb, out_ls);
    hipLaunchKernelGGL(lse_kernel,         dim3(B),    dim3(256), 0, stream, out_ls, cvec);
    hipLaunchKernelGGL(lsub_kernel,        dim3(2000), dim3(256), 0, stream, cvec, out_ls);
}

// Round 6
// 184.325 us; speedup vs baseline: 4.8459x; 1.1296x over previous
//
#include <hip/hip_runtime.h>
#include <math.h>

// Problem constants
#define B 64
#define S 2048
#define H 1024
#define E 512
#define V 32000
#define G4 4096        // 4*H
#define KX 1536        // E+H
#define KC 2560        // E+H+H
#define NVT 500        // number of v-tiles in logits GEMM (V/64)

typedef __attribute__((ext_vector_type(8))) short short8v;
typedef __attribute__((ext_vector_type(4))) float f32x4;

__device__ __forceinline__ ushort f2bf(float f) {
    union { float f; unsigned u; } v; v.f = f;
    unsigned r = v.u + 0x7FFFu + ((v.u >> 16) & 1u);
    return (ushort)(r >> 16);
}

__device__ __forceinline__ float4 ntload4(const float* p) {
    f32x4 v = __builtin_nontemporal_load((const f32x4*)p);
    return make_float4(v[0], v[1], v[2], v[3]);
}

// ---------------- K0: prep = hwh (blocks 0..63) + xfill (blocks 64..447) ----
__global__ __launch_bounds__(256) void prep_kernel(const int* __restrict__ ib,
                                                   const float* __restrict__ emb_W,
                                                   const float* __restrict__ prev_h,
                                                   const float* __restrict__ attn_W,
                                                   float* __restrict__ hwh,
                                                   float* __restrict__ xT) {
    __shared__ float red[256];
    int t = threadIdx.x;
    if (blockIdx.x < 64) {
        int b = blockIdx.x;
        float4 p = *(const float4*)(prev_h + b * H + t * 4);
        float4 w = *(const float4*)(attn_W + t * 4);
        red[t] = p.x * w.x + p.y * w.y + p.z * w.z + p.w * w.w;
        __syncthreads();
        for (int s2 = 128; s2; s2 >>= 1) {
            if (t < s2) red[t] += red[t + s2];
            __syncthreads();
        }
        if (t == 0) hwh[b] = red[0];
    } else {
        int g = (blockIdx.x - 64) * 256 + t;   // 98304 threads
        if (g < E * B) {
            int b = g & 63, k = g >> 6;
            xT[k * B + b] = emb_W[(size_t)ib[b] * E + k];
        } else {
            int g2 = g - E * B;
            int b = g2 & 63, k = g2 >> 6;      // k in [0,H)
            xT[(KX + k) * B + b] = prev_h[b * H + k];
        }
    }
}

// ---------------- K1: fused flash attention over enc (single enc pass) ------
__global__ __launch_bounds__(256) void fused_attn_kernel(const float* __restrict__ enc,
                                                         const float* __restrict__ attn_W,
                                                         const float* __restrict__ attn_b,
                                                         const float* __restrict__ hwh,
                                                         float* __restrict__ scores,
                                                         float* __restrict__ cpart,
                                                         float* __restrict__ mlc) {
    __shared__ float mw[4], lw[4];
    __shared__ float cbuf[4][1024];
    int t = threadIdx.x;
    int lane = t & 63, wid = t >> 6;
    int bx = blockIdx.x;
    int b = bx >> 5, chunk = bx & 31;
    int s0 = chunk * 64 + wid * 16;

    const float* We = attn_W + H;
    float4 we4[4];
#pragma unroll
    for (int c = 0; c < 4; ++c) we4[c] = *(const float4*)(We + c * 256 + lane * 4);
    float cst = hwh[b] + attn_b[0];

    float m = -INFINITY, l = 0.f;
    float4 ctx4[4] = {{0,0,0,0},{0,0,0,0},{0,0,0,0},{0,0,0,0}};

    const float* rowp = enc + (size_t)s0 * (B * H) + b * H + lane * 4;
    float4 e4[4];
#pragma unroll
    for (int c = 0; c < 4; ++c) e4[c] = ntload4(rowp + c * 256);

    for (int i = 0; i < 16; ++i) {
        float4 cur[4];
#pragma unroll
        for (int c = 0; c < 4; ++c) cur[c] = e4[c];
        if (i < 15) {
            const float* np = rowp + (size_t)(i + 1) * (B * H);
#pragma unroll
            for (int c = 0; c < 4; ++c) e4[c] = ntload4(np + c * 256);
        }
        float acc = 0.f;
#pragma unroll
        for (int c = 0; c < 4; ++c)
            acc += cur[c].x * we4[c].x + cur[c].y * we4[c].y +
                   cur[c].z * we4[c].z + cur[c].w * we4[c].w;
#pragma unroll
        for (int x = 32; x; x >>= 1) acc += __shfl_xor(acc, x);
        float score = acc + cst;
        if (lane == 0) scores[b * S + s0 + i] = score;
        float nm = fmaxf(m, score);
        float sc = expf(m - nm);
        float w = expf(score - nm);
        l = l * sc + w;
        m = nm;
#pragma unroll
        for (int c = 0; c < 4; ++c) {
            ctx4[c].x = ctx4[c].x * sc + w * cur[c].x;
            ctx4[c].y = ctx4[c].y * sc + w * cur[c].y;
            ctx4[c].z = ctx4[c].z * sc + w * cur[c].z;
            ctx4[c].w = ctx4[c].w * sc + w * cur[c].w;
        }
    }

    if (lane == 0) { mw[wid] = m; lw[wid] = l; }
    __syncthreads();
    float M = fmaxf(fmaxf(mw[0], mw[1]), fmaxf(mw[2], mw[3]));
    float L = lw[0] * expf(mw[0] - M) + lw[1] * expf(mw[1] - M) +
              lw[2] * expf(mw[2] - M) + lw[3] * expf(mw[3] - M);
    float msc = expf(m - M);
#pragma unroll
    for (int c = 0; c < 4; ++c) {
        float4 v = ctx4[c];
        v.x *= msc; v.y *= msc; v.z *= msc; v.w *= msc;
        *(float4*)&cbuf[wid][c * 256 + lane * 4] = v;
    }
    __syncthreads();
    if (wid == 0) {
#pragma unroll
        for (int c = 0; c < 4; ++c) {
            int h = c * 256 + lane * 4;
            float4 a0 = *(float4*)&cbuf[0][h];
            float4 a1 = *(float4*)&cbuf[1][h];
            float4 a2 = *(float4*)&cbuf[2][h];
            float4 a3 = *(float4*)&cbuf[3][h];
            float4 s4 = make_float4(a0.x + a1.x + a2.x + a3.x,
                                    a0.y + a1.y + a2.y + a3.y,
                                    a0.z + a1.z + a2.z + a3.z,
                                    a0.w + a1.w + a2.w + a3.w);
            *(float4*)(cpart + (size_t)(chunk * B + b) * H + h) = s4;
        }
    }
    if (t == 0) {
        mlc[(b * 32 + chunk) * 2] = M;
        mlc[(b * 32 + chunk) * 2 + 1] = L;
    }
}

// ---------------- K2: merge partials -> context + attn weights --------------
// 256 blocks: b = blk>>2, quarter q = blk&3 (h range and s range split by 4)
__global__ __launch_bounds__(256) void attn_reduce_kernel(const float* __restrict__ cpart,
                                                          const float* __restrict__ mlc,
                                                          const float* __restrict__ scores,
                                                          float* __restrict__ xT,
                                                          float* __restrict__ attn) {
    __shared__ float Ms[32], Ls[32], Es[32];
    int blk = blockIdx.x;
    int b = blk >> 2, q = blk & 3;
    int t = threadIdx.x;
    if (t < 32) {
        Ms[t] = mlc[(b * 32 + t) * 2];
        Ls[t] = mlc[(b * 32 + t) * 2 + 1];
    }
    __syncthreads();
    float Mg = -INFINITY;
#pragma unroll
    for (int c = 0; c < 32; ++c) Mg = fmaxf(Mg, Ms[c]);
    if (t < 32) Es[t] = expf(Ms[t] - Mg);
    __syncthreads();
    float Lg = 0.f;
#pragma unroll
    for (int c = 0; c < 32; ++c) Lg += Ls[c] * Es[c];
    float inv = 1.f / Lg;
    int h = q * 256 + t;
    float acc = 0.f;
#pragma unroll 4
    for (int c = 0; c < 32; ++c)
        acc += Es[c] * cpart[(size_t)(c * B + b) * H + h];
    xT[(E + h) * B + b] = acc * inv;
    // attn weights: this block handles s in [q*512, q*512+512)
#pragma unroll
    for (int i = 0; i < 2; ++i) {
        int s = q * 512 + i * 256 + t;
        attn[b * S + s] = expf(scores[b * S + s] - Mg) * inv;
    }
}

// ---------------- K3: gates GEMM (M=4096, N=64, K=2560 in 8 chunks) ---------
__global__ __launch_bounds__(256) void gates_gemm(const float* __restrict__ W_ih,
                                                  const float* __restrict__ W_hh,
                                                  const float* __restrict__ xT,
                                                  float* __restrict__ gpart) {
    __shared__ float Wt[64][68];
    __shared__ float Xt[64][68];
    int t = threadIdx.x;
    int rtile = blockIdx.x >> 3, ks = blockIdx.x & 7;   // 512 blocks
    int r0 = rtile * 64;
    int rr0 = (t >> 4) * 4;
    int c0 = (t & 15) * 4;
    int sv = t >> 4;
    int sk = (t & 15) * 4;
    float acc[4][4] = {{0.f}};
    for (int kt = 0; kt < 5; ++kt) {
        int kb = ks * 320 + kt * 64;
        const float* wbase;
        int wstride;
        if (kb < KX) { wbase = W_ih + kb; wstride = KX; }
        else         { wbase = W_hh + (kb - KX); wstride = H; }
        __syncthreads();
#pragma unroll
        for (int g = 0; g < 4; ++g) {
            int vv = sv + g * 16;
            *(float4*)&Wt[vv][sk] = *(const float4*)(wbase + (size_t)(r0 + vv) * wstride + sk);
            *(float4*)&Xt[vv][sk] = *(const float4*)(xT + (size_t)(kb + vv) * B + sk);
        }
        __syncthreads();
#pragma unroll
        for (int k0 = 0; k0 < 64; k0 += 4) {
            float w[4][4], x[4][4];
#pragma unroll
            for (int ri = 0; ri < 4; ++ri) *(float4*)w[ri] = *(const float4*)&Wt[rr0 + ri][k0];
#pragma unroll
            for (int kj = 0; kj < 4; ++kj) *(float4*)x[kj] = *(const float4*)&Xt[k0 + kj][c0];
#pragma unroll
            for (int kj = 0; kj < 4; ++kj)
#pragma unroll
                for (int ri = 0; ri < 4; ++ri)
#pragma unroll
                    for (int ci = 0; ci < 4; ++ci)
                        acc[ri][ci] += w[ri][kj] * x[kj][ci];
        }
    }
#pragma unroll
    for (int ri = 0; ri < 4; ++ri) {
        float4 o4 = make_float4(acc[ri][0], acc[ri][1], acc[ri][2], acc[ri][3]);
        *(float4*)(gpart + (size_t)ks * (G4 * B) + (size_t)(r0 + rr0 + ri) * B + c0) = o4;
    }
}

// ---------------- K4: LSTM elementwise (8 partials, emits bf16 hb[b][k]) ----
__global__ __launch_bounds__(256) void lstm_kernel(const float* __restrict__ gpart,
                                                   const float* __restrict__ b_ih,
                                                   const float* __restrict__ b_hh,
                                                   const float* __restrict__ prev_c,
                                                   float* __restrict__ hidden_out,
                                                   float* __restrict__ cell_out,
                                                   ushort* __restrict__ hb) {
    int t = blockIdx.x * 256 + threadIdx.x;  // 65536
    int b = t & 63, h = t >> 6;
    float g[4];
#pragma unroll
    for (int q = 0; q < 4; ++q) {
        int r = h + q * H;
        float a = b_ih[r] + b_hh[r];
#pragma unroll
        for (int ks = 0; ks < 8; ++ks) a += gpart[(size_t)ks * (G4 * B) + r * B + b];
        g[q] = a;
    }
    float ig = 1.f / (1.f + expf(-g[0]));
    float fg = 1.f / (1.f + expf(-g[1]));
    float gg = tanhf(g[2]);
    float og = 1.f / (1.f + expf(-g[3]));
    float c = fg * prev_c[b * H + h] + ig * gg;
    float hd = og * tanhf(c);
    cell_out[b * H + h] = c;
    hidden_out[b * H + h] = hd;
    hb[b * H + h] = f2bf(hd);
}

// ---------------- K5: logits via bf16 MFMA + inline partial logsumexp -------
__global__ __launch_bounds__(256) void logits_mfma(const float* __restrict__ W,
                                                   const float* __restrict__ ob,
                                                   const ushort* __restrict__ hb,
                                                   float* __restrict__ outl,
                                                   float* __restrict__ lsp) {
    __shared__ ushort Wt[64 * 64];   // [v][k] bf16, swizzled
    __shared__ ushort Bt[64 * 64];   // [b][k] bf16, swizzled
    __shared__ float  Ct[64][68];    // [b][v] transpose buffer
    int t = threadIdx.x;
    int lane = t & 63, wid = t >> 6;
    int v0 = blockIdx.x * 64;

    int srow = t >> 2;               // staging row 0..63
    int sq = t & 3;                  // 16-float quarter within row

    f32x4 acc[4] = {{0.f,0.f,0.f,0.f},{0.f,0.f,0.f,0.f},{0.f,0.f,0.f,0.f},{0.f,0.f,0.f,0.f}};

    int r = lane & 15, g = lane >> 4;
    int arow = wid * 16 + r;
    int aswz = (arow & 7) << 4;
    unsigned abase = arow * 128;

    for (int kt = 0; kt < 16; ++kt) {
        int k0 = kt * 64;
        __syncthreads();
        {
            const float* src = W + (size_t)(v0 + srow) * H + k0 + sq * 16;
            float4 f0 = ntload4(src + 0);
            float4 f1 = ntload4(src + 4);
            float4 f2 = ntload4(src + 8);
            float4 f3 = ntload4(src + 12);
            short8v w0, w1;
            w0[0] = (short)f2bf(f0.x); w0[1] = (short)f2bf(f0.y);
            w0[2] = (short)f2bf(f0.z); w0[3] = (short)f2bf(f0.w);
            w0[4] = (short)f2bf(f1.x); w0[5] = (short)f2bf(f1.y);
            w0[6] = (short)f2bf(f1.z); w0[7] = (short)f2bf(f1.w);
            w1[0] = (short)f2bf(f2.x); w1[1] = (short)f2bf(f2.y);
            w1[2] = (short)f2bf(f2.z); w1[3] = (short)f2bf(f2.w);
            w1[4] = (short)f2bf(f3.x); w1[5] = (short)f2bf(f3.y);
            w1[6] = (short)f2bf(f3.z); w1[7] = (short)f2bf(f3.w);
            unsigned rb = srow * 128;
            unsigned sw = (srow & 7) << 4;
            *(short8v*)((char*)Wt + rb + ((sq * 32 + 0) ^ sw))  = w0;
            *(short8v*)((char*)Wt + rb + ((sq * 32 + 16) ^ sw)) = w1;
        }
        {
            const ushort* hsrc = hb + (size_t)srow * H + k0 + sq * 16;
            uint4 h0 = *(const uint4*)(hsrc);
            uint4 h1 = *(const uint4*)(hsrc + 8);
            unsigned rb = srow * 128;
            unsigned sw = (srow & 7) << 4;
            *(uint4*)((char*)Bt + rb + ((sq * 32 + 0) ^ sw))  = h0;
            *(uint4*)((char*)Bt + rb + ((sq * 32 + 16) ^ sw)) = h1;
        }
        __syncthreads();
#pragma unroll
        for (int kk = 0; kk < 2; ++kk) {
            unsigned koff = kk * 64 + g * 16;
            short8v a = *(short8v*)((char*)Wt + abase + (koff ^ aswz));
#pragma unroll
            for (int bt = 0; bt < 4; ++bt) {
                int brow = bt * 16 + r;
                short8v bb = *(short8v*)((char*)Bt + brow * 128 + (koff ^ ((brow & 7) << 4)));
                acc[bt] = __builtin_amdgcn_mfma_f32_16x16x32_bf16(a, bb, acc[bt], 0, 0, 0);
            }
        }
    }
    __syncthreads();
    // bias + transpose through LDS (C/D layout: col=lane&15, row=(lane>>4)*4+j)
    float bias[4];
#pragma unroll
    for (int j = 0; j < 4; ++j) bias[j] = ob[v0 + wid * 16 + g * 4 + j];
#pragma unroll
    for (int bt = 0; bt < 4; ++bt)
#pragma unroll
        for (int j = 0; j < 4; ++j)
            Ct[bt * 16 + r][wid * 16 + g * 4 + j] = acc[bt][j] + bias[j];
    __syncthreads();
    int ob_ = t >> 2;
    int vq = (t & 3) * 16;
    float4 vals[4];
    float pm = -3.4e38f;
#pragma unroll
    for (int c = 0; c < 4; ++c) {
        vals[c] = *(float4*)&Ct[ob_][vq + c * 4];
        pm = fmaxf(pm, fmaxf(fmaxf(vals[c].x, vals[c].y), fmaxf(vals[c].z, vals[c].w)));
        *(float4*)(outl + (size_t)ob_ * V + v0 + vq + c * 4) = vals[c];
    }
    float ps = 0.f;
#pragma unroll
    for (int c = 0; c < 4; ++c)
        ps += expf(vals[c].x - pm) + expf(vals[c].y - pm) +
              expf(vals[c].z - pm) + expf(vals[c].w - pm);
    // merge across the 4 threads sharing this b-row (adjacent lanes)
#pragma unroll
    for (int x = 1; x <= 2; x <<= 1) {
        float om = __shfl_xor(pm, x);
        float os = __shfl_xor(ps, x);
        float nm = fmaxf(pm, om);
        ps = ps * expf(pm - nm) + os * expf(om - nm);
        pm = nm;
    }
    if ((t & 3) == 0) {
        lsp[((size_t)ob_ * NVT + blockIdx.x) * 2]     = pm;
        lsp[((size_t)ob_ * NVT + blockIdx.x) * 2 + 1] = ps;
    }
}

// ---------------- K6: merge lse partials + log_softmax subtract -------------
// 2048 blocks: b = blk>>5, chunk = blk&31 (1000 floats each)
__global__ __launch_bounds__(256) void lsub_kernel(const float* __restrict__ lsp,
                                                   float* __restrict__ lg) {
    __shared__ float rm[256], rl[256];
    int blk = blockIdx.x;
    int b = blk >> 5, chunk = blk & 31;
    int t = threadIdx.x;
    const float* pb = lsp + (size_t)b * (NVT * 2);
    float m = pb[t * 2], l = pb[t * 2 + 1];
    int i2 = t + 256;
    if (i2 < NVT) {
        float m1 = pb[i2 * 2], l1 = pb[i2 * 2 + 1];
        float nm = fmaxf(m, m1);
        l = l * expf(m - nm) + l1 * expf(m1 - nm);
        m = nm;
    }
    rm[t] = m; rl[t] = l; __syncthreads();
    for (int s2 = 128; s2; s2 >>= 1) {
        if (t < s2) {
            float m2 = rm[t + s2], l2 = rl[t + s2];
            float nm = fmaxf(rm[t], m2);
            rl[t] = rl[t] * expf(rm[t] - nm) + l2 * expf(m2 - nm);
            rm[t] = nm;
        }
        __syncthreads();
    }
    float c = rm[0] + logf(rl[0]);
    if (t < 250) {
        float4* p = (float4*)(lg + (size_t)b * V + chunk * 1000) + t;
        float4 x = *p;
        x.x -= c; x.y -= c; x.z -= c; x.w -= c;
        *p = x;
    }
}

// ---------------- launch ----------------------------------------------------
extern "C" void kernel_launch(void* const* d_in, const int* in_sizes, int n_in,
                              void* d_out, int out_size, void* d_ws, size_t ws_size,
                              hipStream_t stream) {
    const int*   ib      = (const int*)d_in[0];
    const float* prev_h  = (const float*)d_in[1];
    const float* prev_c  = (const float*)d_in[2];
    const float* enc     = (const float*)d_in[3];
    const float* emb_W   = (const float*)d_in[4];
    const float* attn_W  = (const float*)d_in[5];
    const float* attn_b  = (const float*)d_in[6];
    const float* W_ih    = (const float*)d_in[7];
    const float* W_hh    = (const float*)d_in[8];
    const float* b_ih    = (const float*)d_in[9];
    const float* b_hh    = (const float*)d_in[10];
    const float* out_W   = (const float*)d_in[11];
    const float* out_b   = (const float*)d_in[12];

    float* ws = (float*)d_ws;
    // ws layout (floats), total ~10 MB
    float* sc   = ws;                      // 131072  scores (B*S)
    float* hwh  = ws + 131072;             // 64
    float* xT   = ws + 131200;             // 163840  [KC][B]
    float* cp   = ws + 295040;             // 2097152 ctx partials [32][B][H]
    float* gp   = cp;                      // 2097152 gates partials [8][G4][B] (cp dead)
    float* mlc  = ws + 2392192;            // 4096
    ushort* hb  = (ushort*)(ws + 2396288); // 65536 ushorts = bf16 hidden [B][H]
    float* lsp  = ws + 2429056;            // 64000 lse partials [B][NVT][2]

    float* out    = (float*)d_out;
    float* out_ls = out;                         // (B,V)
    float* out_h  = out + (size_t)B * V;         // (B,H)
    float* out_c  = out_h + (size_t)B * H;       // (B,H)
    float* out_a  = out_c + (size_t)B * H;       // (B,S)

    hipLaunchKernelGGL(prep_kernel,        dim3(448),  dim3(256), 0, stream, ib, emb_W, prev_h, attn_W, hwh, xT);
    hipLaunchKernelGGL(fused_attn_kernel,  dim3(2048), dim3(256), 0, stream, enc, attn_W, attn_b, hwh, sc, cp, mlc);
    hipLaunchKernelGGL(attn_reduce_kernel, dim3(256),  dim3(256), 0, stream, cp, mlc, sc, xT, out_a);
    hipLaunchKernelGGL(gates_gemm,         dim3(512),  dim3(256), 0, stream, W_ih, W_hh, xT, gp);
    hipLaunchKernelGGL(lstm_kernel,        dim3(256),  dim3(256), 0, stream, gp, b_ih, b_hh, prev_c, out_h, out_c, hb);
    hipLaunchKernelGGL(logits_mfma,        dim3(NVT),  dim3(256), 0, stream, out_W, out_b, hb, out_ls, lsp);
    hipLaunchKernelGGL(lsub_kernel,        dim3(2048), dim3(256), 0, stream, lsp, out_ls);
}

// Round 7
// 168.635 us; speedup vs baseline: 5.2968x; 1.0930x over previous
//
#include <hip/hip_runtime.h>
#include <math.h>

// Problem constants
#define B 64
#define S 2048
#define H 1024
#define E 512
#define V 32000
#define G4 4096        // 4*H
#define KX 1536        // E+H
#define KC 2560        // E+H+H
#define NVT 500        // number of v-tiles in logits GEMM (V/64)

typedef __attribute__((ext_vector_type(8))) short short8v;
typedef __attribute__((ext_vector_type(4))) float f32x4;

__device__ __forceinline__ ushort f2bf(float f) {
    union { float f; unsigned u; } v; v.f = f;
    unsigned r = v.u + 0x7FFFu + ((v.u >> 16) & 1u);
    return (ushort)(r >> 16);
}

__device__ __forceinline__ float4 ntload4(const float* p) {
    f32x4 v = __builtin_nontemporal_load((const f32x4*)p);
    return make_float4(v[0], v[1], v[2], v[3]);
}

// ---------------- K1: fused flash attention over enc (single enc pass) ------
// 1024 blocks: b = blk>>4, cpair = blk&15 -> s-chunks {2*cpair, 2*cpair+1}.
// hwh computed inline per block. Online softmax + ctx accumulated across both
// chunks; one partial (M,L,ctx) per (b,cpair).
__global__ __launch_bounds__(256) void fused_attn_kernel(const float* __restrict__ enc,
                                                         const float* __restrict__ attn_W,
                                                         const float* __restrict__ attn_b,
                                                         const float* __restrict__ prev_h,
                                                         float* __restrict__ scores,
                                                         float* __restrict__ cpart,
                                                         float* __restrict__ mlc) {
    __shared__ float red[256];
    __shared__ float mw[4], lw[4];
    __shared__ float cbuf[4][1024];
    int t = threadIdx.x;
    int lane = t & 63, wid = t >> 6;
    int b = blockIdx.x >> 4, cpair = blockIdx.x & 15;

    // inline hwh[b] = dot(prev_h[b,:], attn_W[0:H])
    {
        float4 p = *(const float4*)(prev_h + b * H + t * 4);
        float4 w = *(const float4*)(attn_W + t * 4);
        red[t] = p.x * w.x + p.y * w.y + p.z * w.z + p.w * w.w;
        __syncthreads();
        for (int s2 = 128; s2; s2 >>= 1) {
            if (t < s2) red[t] += red[t + s2];
            __syncthreads();
        }
    }
    float cst = red[0] + attn_b[0];

    const float* We = attn_W + H;
    float4 we4[4];
#pragma unroll
    for (int c = 0; c < 4; ++c) we4[c] = *(const float4*)(We + c * 256 + lane * 4);

    float m = -INFINITY, l = 0.f;
    float4 ctx4[4] = {{0,0,0,0},{0,0,0,0},{0,0,0,0},{0,0,0,0}};

    for (int cc = 0; cc < 2; ++cc) {
        int chunk = cpair * 2 + cc;
        int s0 = chunk * 64 + wid * 16;
        const float* rowp = enc + (size_t)s0 * (B * H) + b * H + lane * 4;
        float4 e4[4];
#pragma unroll
        for (int c = 0; c < 4; ++c) e4[c] = ntload4(rowp + c * 256);

        for (int i = 0; i < 16; ++i) {
            float4 cur[4];
#pragma unroll
            for (int c = 0; c < 4; ++c) cur[c] = e4[c];
            if (i < 15) {
                const float* np = rowp + (size_t)(i + 1) * (B * H);
#pragma unroll
                for (int c = 0; c < 4; ++c) e4[c] = ntload4(np + c * 256);
            }
            float acc = 0.f;
#pragma unroll
            for (int c = 0; c < 4; ++c)
                acc += cur[c].x * we4[c].x + cur[c].y * we4[c].y +
                       cur[c].z * we4[c].z + cur[c].w * we4[c].w;
#pragma unroll
            for (int x = 32; x; x >>= 1) acc += __shfl_xor(acc, x);
            float score = acc + cst;
            if (lane == 0) scores[b * S + s0 + i] = score;
            float nm = fmaxf(m, score);
            float sc = expf(m - nm);
            float w = expf(score - nm);
            l = l * sc + w;
            m = nm;
#pragma unroll
            for (int c = 0; c < 4; ++c) {
                ctx4[c].x = ctx4[c].x * sc + w * cur[c].x;
                ctx4[c].y = ctx4[c].y * sc + w * cur[c].y;
                ctx4[c].z = ctx4[c].z * sc + w * cur[c].z;
                ctx4[c].w = ctx4[c].w * sc + w * cur[c].w;
            }
        }
    }

    if (lane == 0) { mw[wid] = m; lw[wid] = l; }
    __syncthreads();
    float M = fmaxf(fmaxf(mw[0], mw[1]), fmaxf(mw[2], mw[3]));
    float L = lw[0] * expf(mw[0] - M) + lw[1] * expf(mw[1] - M) +
              lw[2] * expf(mw[2] - M) + lw[3] * expf(mw[3] - M);
    float msc = expf(m - M);
#pragma unroll
    for (int c = 0; c < 4; ++c) {
        float4 v = ctx4[c];
        v.x *= msc; v.y *= msc; v.z *= msc; v.w *= msc;
        *(float4*)&cbuf[wid][c * 256 + lane * 4] = v;
    }
    __syncthreads();
    if (wid == 0) {
#pragma unroll
        for (int c = 0; c < 4; ++c) {
            int h = c * 256 + lane * 4;
            float4 a0 = *(float4*)&cbuf[0][h];
            float4 a1 = *(float4*)&cbuf[1][h];
            float4 a2 = *(float4*)&cbuf[2][h];
            float4 a3 = *(float4*)&cbuf[3][h];
            float4 s4 = make_float4(a0.x + a1.x + a2.x + a3.x,
                                    a0.y + a1.y + a2.y + a3.y,
                                    a0.z + a1.z + a2.z + a3.z,
                                    a0.w + a1.w + a2.w + a3.w);
            *(float4*)(cpart + (size_t)(cpair * B + b) * H + h) = s4;
        }
    }
    if (t == 0) {
        mlc[(b * 16 + cpair) * 2] = M;
        mlc[(b * 16 + cpair) * 2 + 1] = L;
    }
}

// ---------------- K2: merge partials -> xb(bf16) context + weights + fill ---
// 256 blocks: b = blk>>2, quarter q = blk&3
__global__ __launch_bounds__(256) void attn_reduce_kernel(const float* __restrict__ cpart,
                                                          const float* __restrict__ mlc,
                                                          const float* __restrict__ scores,
                                                          const int* __restrict__ ib,
                                                          const float* __restrict__ emb_W,
                                                          const float* __restrict__ prev_h,
                                                          ushort* __restrict__ xb,
                                                          float* __restrict__ attn) {
    __shared__ float Ms[16], Ls[16], Es[16];
    int blk = blockIdx.x;
    int b = blk >> 2, q = blk & 3;
    int t = threadIdx.x;
    if (t < 16) {
        Ms[t] = mlc[(b * 16 + t) * 2];
        Ls[t] = mlc[(b * 16 + t) * 2 + 1];
    }
    __syncthreads();
    float Mg = -INFINITY;
#pragma unroll
    for (int c = 0; c < 16; ++c) Mg = fmaxf(Mg, Ms[c]);
    if (t < 16) Es[t] = expf(Ms[t] - Mg);
    __syncthreads();
    float Lg = 0.f;
#pragma unroll
    for (int c = 0; c < 16; ++c) Lg += Ls[c] * Es[c];
    float inv = 1.f / Lg;
    // context quarter
    int h = q * 256 + t;
    float acc = 0.f;
#pragma unroll 4
    for (int c = 0; c < 16; ++c)
        acc += Es[c] * cpart[(size_t)(c * B + b) * H + h];
    xb[(size_t)b * KC + E + h] = f2bf(acc * inv);
    // attn weights: s in [q*512, q*512+512)
#pragma unroll
    for (int i = 0; i < 2; ++i) {
        int s = q * 512 + i * 256 + t;
        attn[b * S + s] = expf(scores[b * S + s] - Mg) * inv;
    }
    // xb fill (emb + prev_h): j range [q*384, q*384+384)
#pragma unroll
    for (int i = 0; i < 2; ++i) {
        int j = q * 384 + i * 256 + t;
        if (i == 1 && t >= 128) break;
        if (j < E) xb[(size_t)b * KC + j] = f2bf(emb_W[(size_t)ib[b] * E + j]);
        else       xb[(size_t)b * KC + KX + (j - E)] = f2bf(prev_h[b * H + (j - E)]);
    }
}

// ---------------- K3: gates GEMM via bf16 MFMA ------------------------------
// gpart[ks][r][b] = sum_{k in 320-chunk ks} W[r,k]*x[b,k]. 512 blocks.
__global__ __launch_bounds__(256) void gates_mfma(const float* __restrict__ W_ih,
                                                  const float* __restrict__ W_hh,
                                                  const ushort* __restrict__ xb,
                                                  float* __restrict__ gpart) {
    __shared__ ushort Wt[64 * 64];   // [r][k] bf16, swizzled
    __shared__ ushort Bt[64 * 64];   // [b][k] bf16, swizzled
    int t = threadIdx.x;
    int lane = t & 63, wid = t >> 6;
    int rtile = blockIdx.x >> 3, ks = blockIdx.x & 7;
    int r0 = rtile * 64;

    int srow = t >> 2;
    int sq = t & 3;

    f32x4 acc[4] = {{0.f,0.f,0.f,0.f},{0.f,0.f,0.f,0.f},{0.f,0.f,0.f,0.f},{0.f,0.f,0.f,0.f}};

    int r = lane & 15, g = lane >> 4;
    int arow = wid * 16 + r;
    int aswz = (arow & 7) << 4;
    unsigned abase = arow * 128;

    for (int kt = 0; kt < 5; ++kt) {
        int kb = ks * 320 + kt * 64;
        const float* wbase;
        int wstride;
        if (kb < KX) { wbase = W_ih + kb; wstride = KX; }
        else         { wbase = W_hh + (kb - KX); wstride = H; }
        __syncthreads();
        {
            const float* src = wbase + (size_t)(r0 + srow) * wstride + sq * 16;
            float4 f0 = ntload4(src + 0);
            float4 f1 = ntload4(src + 4);
            float4 f2 = ntload4(src + 8);
            float4 f3 = ntload4(src + 12);
            short8v w0, w1;
            w0[0] = (short)f2bf(f0.x); w0[1] = (short)f2bf(f0.y);
            w0[2] = (short)f2bf(f0.z); w0[3] = (short)f2bf(f0.w);
            w0[4] = (short)f2bf(f1.x); w0[5] = (short)f2bf(f1.y);
            w0[6] = (short)f2bf(f1.z); w0[7] = (short)f2bf(f1.w);
            w1[0] = (short)f2bf(f2.x); w1[1] = (short)f2bf(f2.y);
            w1[2] = (short)f2bf(f2.z); w1[3] = (short)f2bf(f2.w);
            w1[4] = (short)f2bf(f3.x); w1[5] = (short)f2bf(f3.y);
            w1[6] = (short)f2bf(f3.z); w1[7] = (short)f2bf(f3.w);
            unsigned rb = srow * 128;
            unsigned sw = (srow & 7) << 4;
            *(short8v*)((char*)Wt + rb + ((sq * 32 + 0) ^ sw))  = w0;
            *(short8v*)((char*)Wt + rb + ((sq * 32 + 16) ^ sw)) = w1;
        }
        {
            const ushort* hsrc = xb + (size_t)srow * KC + kb + sq * 16;
            uint4 h0 = *(const uint4*)(hsrc);
            uint4 h1 = *(const uint4*)(hsrc + 8);
            unsigned rb = srow * 128;
            unsigned sw = (srow & 7) << 4;
            *(uint4*)((char*)Bt + rb + ((sq * 32 + 0) ^ sw))  = h0;
            *(uint4*)((char*)Bt + rb + ((sq * 32 + 16) ^ sw)) = h1;
        }
        __syncthreads();
#pragma unroll
        for (int kk = 0; kk < 2; ++kk) {
            unsigned koff = kk * 64 + g * 16;
            short8v a = *(short8v*)((char*)Wt + abase + (koff ^ aswz));
#pragma unroll
            for (int bt = 0; bt < 4; ++bt) {
                int brow = bt * 16 + r;
                short8v bb = *(short8v*)((char*)Bt + brow * 128 + (koff ^ ((brow & 7) << 4)));
                acc[bt] = __builtin_amdgcn_mfma_f32_16x16x32_bf16(a, bb, acc[bt], 0, 0, 0);
            }
        }
    }
    // direct scatter store: r_global = r0 + wid*16 + g*4 + j; b = bt*16 + r
#pragma unroll
    for (int bt = 0; bt < 4; ++bt) {
        int bcol = bt * 16 + r;
#pragma unroll
        for (int j = 0; j < 4; ++j) {
            int rg = r0 + wid * 16 + g * 4 + j;
            gpart[(size_t)ks * (G4 * B) + (size_t)rg * B + bcol] = acc[bt][j];
        }
    }
}

// ---------------- K4: LSTM elementwise (8 partials, emits bf16 hb[b][k]) ----
__global__ __launch_bounds__(256) void lstm_kernel(const float* __restrict__ gpart,
                                                   const float* __restrict__ b_ih,
                                                   const float* __restrict__ b_hh,
                                                   const float* __restrict__ prev_c,
                                                   float* __restrict__ hidden_out,
                                                   float* __restrict__ cell_out,
                                                   ushort* __restrict__ hb) {
    int t = blockIdx.x * 256 + threadIdx.x;  // 65536
    int b = t & 63, h = t >> 6;
    float g[4];
#pragma unroll
    for (int q = 0; q < 4; ++q) {
        int r = h + q * H;
        float a = b_ih[r] + b_hh[r];
#pragma unroll
        for (int ks = 0; ks < 8; ++ks) a += gpart[(size_t)ks * (G4 * B) + r * B + b];
        g[q] = a;
    }
    float ig = 1.f / (1.f + expf(-g[0]));
    float fg = 1.f / (1.f + expf(-g[1]));
    float gg = tanhf(g[2]);
    float og = 1.f / (1.f + expf(-g[3]));
    float c = fg * prev_c[b * H + h] + ig * gg;
    float hd = og * tanhf(c);
    cell_out[b * H + h] = c;
    hidden_out[b * H + h] = hd;
    hb[b * H + h] = f2bf(hd);
}

// ---------------- K5: logits via bf16 MFMA + inline partial logsumexp -------
__global__ __launch_bounds__(256) void logits_mfma(const float* __restrict__ W,
                                                   const float* __restrict__ ob,
                                                   const ushort* __restrict__ hb,
                                                   float* __restrict__ outl,
                                                   float* __restrict__ lsp) {
    __shared__ ushort Wt[64 * 64];   // [v][k] bf16, swizzled
    __shared__ ushort Bt[64 * 64];   // [b][k] bf16, swizzled
    __shared__ float  Ct[64][68];    // [b][v] transpose buffer
    int t = threadIdx.x;
    int lane = t & 63, wid = t >> 6;
    int v0 = blockIdx.x * 64;

    int srow = t >> 2;
    int sq = t & 3;

    f32x4 acc[4] = {{0.f,0.f,0.f,0.f},{0.f,0.f,0.f,0.f},{0.f,0.f,0.f,0.f},{0.f,0.f,0.f,0.f}};

    int r = lane & 15, g = lane >> 4;
    int arow = wid * 16 + r;
    int aswz = (arow & 7) << 4;
    unsigned abase = arow * 128;

    for (int kt = 0; kt < 16; ++kt) {
        int k0 = kt * 64;
        __syncthreads();
        {
            const float* src = W + (size_t)(v0 + srow) * H + k0 + sq * 16;
            float4 f0 = ntload4(src + 0);
            float4 f1 = ntload4(src + 4);
            float4 f2 = ntload4(src + 8);
            float4 f3 = ntload4(src + 12);
            short8v w0, w1;
            w0[0] = (short)f2bf(f0.x); w0[1] = (short)f2bf(f0.y);
            w0[2] = (short)f2bf(f0.z); w0[3] = (short)f2bf(f0.w);
            w0[4] = (short)f2bf(f1.x); w0[5] = (short)f2bf(f1.y);
            w0[6] = (short)f2bf(f1.z); w0[7] = (short)f2bf(f1.w);
            w1[0] = (short)f2bf(f2.x); w1[1] = (short)f2bf(f2.y);
            w1[2] = (short)f2bf(f2.z); w1[3] = (short)f2bf(f2.w);
            w1[4] = (short)f2bf(f3.x); w1[5] = (short)f2bf(f3.y);
            w1[6] = (short)f2bf(f3.z); w1[7] = (short)f2bf(f3.w);
            unsigned rb = srow * 128;
            unsigned sw = (srow & 7) << 4;
            *(short8v*)((char*)Wt + rb + ((sq * 32 + 0) ^ sw))  = w0;
            *(short8v*)((char*)Wt + rb + ((sq * 32 + 16) ^ sw)) = w1;
        }
        {
            const ushort* hsrc = hb + (size_t)srow * H + k0 + sq * 16;
            uint4 h0 = *(const uint4*)(hsrc);
            uint4 h1 = *(const uint4*)(hsrc + 8);
            unsigned rb = srow * 128;
            unsigned sw = (srow & 7) << 4;
            *(uint4*)((char*)Bt + rb + ((sq * 32 + 0) ^ sw))  = h0;
            *(uint4*)((char*)Bt + rb + ((sq * 32 + 16) ^ sw)) = h1;
        }
        __syncthreads();
#pragma unroll
        for (int kk = 0; kk < 2; ++kk) {
            unsigned koff = kk * 64 + g * 16;
            short8v a = *(short8v*)((char*)Wt + abase + (koff ^ aswz));
#pragma unroll
            for (int bt = 0; bt < 4; ++bt) {
                int brow = bt * 16 + r;
                short8v bb = *(short8v*)((char*)Bt + brow * 128 + (koff ^ ((brow & 7) << 4)));
                acc[bt] = __builtin_amdgcn_mfma_f32_16x16x32_bf16(a, bb, acc[bt], 0, 0, 0);
            }
        }
    }
    __syncthreads();
    float bias[4];
#pragma unroll
    for (int j = 0; j < 4; ++j) bias[j] = ob[v0 + wid * 16 + g * 4 + j];
#pragma unroll
    for (int bt = 0; bt < 4; ++bt)
#pragma unroll
        for (int j = 0; j < 4; ++j)
            Ct[bt * 16 + r][wid * 16 + g * 4 + j] = acc[bt][j] + bias[j];
    __syncthreads();
    int ob_ = t >> 2;
    int vq = (t & 3) * 16;
    float4 vals[4];
    float pm = -3.4e38f;
#pragma unroll
    for (int c = 0; c < 4; ++c) {
        vals[c] = *(float4*)&Ct[ob_][vq + c * 4];
        pm = fmaxf(pm, fmaxf(fmaxf(vals[c].x, vals[c].y), fmaxf(vals[c].z, vals[c].w)));
        *(float4*)(outl + (size_t)ob_ * V + v0 + vq + c * 4) = vals[c];
    }
    float ps = 0.f;
#pragma unroll
    for (int c = 0; c < 4; ++c)
        ps += expf(vals[c].x - pm) + expf(vals[c].y - pm) +
              expf(vals[c].z - pm) + expf(vals[c].w - pm);
#pragma unroll
    for (int x = 1; x <= 2; x <<= 1) {
        float om = __shfl_xor(pm, x);
        float os = __shfl_xor(ps, x);
        float nm = fmaxf(pm, om);
        ps = ps * expf(pm - nm) + os * expf(om - nm);
        pm = nm;
    }
    if ((t & 3) == 0) {
        lsp[((size_t)ob_ * NVT + blockIdx.x) * 2]     = pm;
        lsp[((size_t)ob_ * NVT + blockIdx.x) * 2 + 1] = ps;
    }
}

// ---------------- K6: merge lse partials + log_softmax subtract -------------
__global__ __launch_bounds__(256) void lsub_kernel(const float* __restrict__ lsp,
                                                   float* __restrict__ lg) {
    __shared__ float rm[256], rl[256];
    int blk = blockIdx.x;
    int b = blk >> 5, chunk = blk & 31;
    int t = threadIdx.x;
    const float* pb = lsp + (size_t)b * (NVT * 2);
    float m = pb[t * 2], l = pb[t * 2 + 1];
    int i2 = t + 256;
    if (i2 < NVT) {
        float m1 = pb[i2 * 2], l1 = pb[i2 * 2 + 1];
        float nm = fmaxf(m, m1);
        l = l * expf(m - nm) + l1 * expf(m1 - nm);
        m = nm;
    }
    rm[t] = m; rl[t] = l; __syncthreads();
    for (int s2 = 128; s2; s2 >>= 1) {
        if (t < s2) {
            float m2 = rm[t + s2], l2 = rl[t + s2];
            float nm = fmaxf(rm[t], m2);
            rl[t] = rl[t] * expf(rm[t] - nm) + l2 * expf(m2 - nm);
            rm[t] = nm;
        }
        __syncthreads();
    }
    float c = rm[0] + logf(rl[0]);
    if (t < 250) {
        float4* p = (float4*)(lg + (size_t)b * V + chunk * 1000) + t;
        float4 x = *p;
        x.x -= c; x.y -= c; x.z -= c; x.w -= c;
        *p = x;
    }
}

// ---------------- launch ----------------------------------------------------
extern "C" void kernel_launch(void* const* d_in, const int* in_sizes, int n_in,
                              void* d_out, int out_size, void* d_ws, size_t ws_size,
                              hipStream_t stream) {
    const int*   ib      = (const int*)d_in[0];
    const float* prev_h  = (const float*)d_in[1];
    const float* prev_c  = (const float*)d_in[2];
    const float* enc     = (const float*)d_in[3];
    const float* emb_W   = (const float*)d_in[4];
    const float* attn_W  = (const float*)d_in[5];
    const float* attn_b  = (const float*)d_in[6];
    const float* W_ih    = (const float*)d_in[7];
    const float* W_hh    = (const float*)d_in[8];
    const float* b_ih    = (const float*)d_in[9];
    const float* b_hh    = (const float*)d_in[10];
    const float* out_W   = (const float*)d_in[11];
    const float* out_b   = (const float*)d_in[12];

    float* ws = (float*)d_ws;
    // ws layout (floats), total ~13.8 MB
    float* sc   = ws;                        // 131072  scores (B*S)
    float* cp   = ws + 131072;               // 1048576 ctx partials [16][B][H]
    float* gp   = ws + 1179648;              // 2097152 gates partials [8][G4][B]
    float* mlc  = ws + 3276800;              // 2048
    ushort* xb  = (ushort*)(ws + 3278848);   // 163840 ushorts = bf16 x_cat [B][KC]
    ushort* hb  = (ushort*)(ws + 3360768);   // 65536 ushorts = bf16 hidden [B][H]
    float* lsp  = ws + 3393536;              // 64000 lse partials [B][NVT][2]

    float* out    = (float*)d_out;
    float* out_ls = out;                         // (B,V)
    float* out_h  = out + (size_t)B * V;         // (B,H)
    float* out_c  = out_h + (size_t)B * H;       // (B,H)
    float* out_a  = out_c + (size_t)B * H;       // (B,S)

    hipLaunchKernelGGL(fused_attn_kernel,  dim3(1024), dim3(256), 0, stream, enc, attn_W, attn_b, prev_h, sc, cp, mlc);
    hipLaunchKernelGGL(attn_reduce_kernel, dim3(256),  dim3(256), 0, stream, cp, mlc, sc, ib, emb_W, prev_h, xb, out_a);
    hipLaunchKernelGGL(gates_mfma,         dim3(512),  dim3(256), 0, stream, W_ih, W_hh, xb, gp);
    hipLaunchKernelGGL(lstm_kernel,        dim3(256),  dim3(256), 0, stream, gp, b_ih, b_hh, prev_c, out_h, out_c, hb);
    hipLaunchKernelGGL(logits_mfma,        dim3(NVT),  dim3(256), 0, stream, out_W, out_b, hb, out_ls, lsp);
    hipLaunchKernelGGL(lsub_kernel,        dim3(2048), dim3(256), 0, stream, lsp, out_ls);
}